// Round 5
// baseline (4308.886 us; speedup 1.0000x reference)
//
#include <hip/hip_runtime.h>
#include <hip/hip_bf16.h>

typedef __bf16 bf16x8 __attribute__((ext_vector_type(8)));
typedef float  f32x4  __attribute__((ext_vector_type(4)));

#define BM 256
#define BN 256
#define BK 64
#define THREADS 512

__device__ __forceinline__ void gload_lds16(const void* g, void* l) {
  __builtin_amdgcn_global_load_lds(
      (const __attribute__((address_space(1))) void*)g,
      (__attribute__((address_space(3))) void*)l, 16, 0, 0);
}

template<int N> __device__ __forceinline__ void vmwait() {
  if constexpr (N == 0)      asm volatile("s_waitcnt vmcnt(0)" ::: "memory");
  else if constexpr (N == 6) asm volatile("s_waitcnt vmcnt(6)" ::: "memory");
}
__device__ __forceinline__ void phase_barrier() {
  asm volatile("s_barrier" ::: "memory");
}

// ---- fp32 -> bf16 (RNE) ----
__global__ void cvt_x_kernel(const float* __restrict__ in, __bf16* __restrict__ out, long n) {
  long i0 = ((long)blockIdx.x * blockDim.x + threadIdx.x) * 8;
  long stride = (long)gridDim.x * blockDim.x * 8;
  for (long i = i0; i < n; i += stride) {
    float4 f0 = *(const float4*)(in + i);
    float4 f1 = *(const float4*)(in + i + 4);
    bf16x8 v;
    v[0] = (__bf16)f0.x; v[1] = (__bf16)f0.y; v[2] = (__bf16)f0.z; v[3] = (__bf16)f0.w;
    v[4] = (__bf16)f1.x; v[5] = (__bf16)f1.y; v[6] = (__bf16)f1.z; v[7] = (__bf16)f1.w;
    *(bf16x8*)(out + i) = v;
  }
}

// ---- (int32 weight - zp) -> bf16, EXACT for |v|<=255 ----
__global__ void cvt_w_kernel(const int* __restrict__ w, const int* __restrict__ zp,
                             __bf16* __restrict__ out, int K, long n) {
  long i0 = ((long)blockIdx.x * blockDim.x + threadIdx.x) * 8;
  long stride = (long)gridDim.x * blockDim.x * 8;
  for (long i = i0; i < n; i += stride) {
    int4 a = *(const int4*)(w + i);
    int4 b = *(const int4*)(w + i + 4);
    int z = zp[i / K];
    bf16x8 v;
    v[0] = (__bf16)(float)(a.x - z); v[1] = (__bf16)(float)(a.y - z);
    v[2] = (__bf16)(float)(a.z - z); v[3] = (__bf16)(float)(a.w - z);
    v[4] = (__bf16)(float)(b.x - z); v[5] = (__bf16)(float)(b.y - z);
    v[6] = (__bf16)(float)(b.z - z); v[7] = (__bf16)(float)(b.w - z);
    *(bf16x8*)(out + i) = v;
  }
}

// ============ 256x256 GEMM, 4 phases/K-tile, ONE barrier/phase ============
// Per phase: [stage issues] [frag ds_reads] [setprio+16 MFMA (compiler emits
// exact lgkmcnt)] [vmwait once per tile] [s_barrier w/ memory clobber].
// Waves skew within a phase -> LDS pipe overlaps matrix pipe.
// Stage batch for tile t+2 (buf b=t&1): ph1(t):B0,B1  ph2(t):B2,B3,A0
// ph3(t):A2  ph0(t+1):A1,A3.  WAR: each region staged >=1 barrier after its
// last read (B last read ph0; A0 ph1; A2 ph1; A1,A3 ph3 of prev tile); reads
// complete pre-barrier because each ds_read feeds an MFMA in its own phase.
// RAW: vmwait<6> at end-ph3(t) retires batch t+1 exactly (8 oldest), leaving
// batch t+2's 6 in flight.  Loop runs t = 0 .. NT-2 (NT-2 is the drain iter —
// round-4 bug was stopping at NT-3, skipping tile NT-2 entirely).
__global__ __launch_bounds__(THREADS, 2)
void qlin_gemm(const __bf16* __restrict__ A, const __bf16* __restrict__ B,
               const float* __restrict__ scale, const float* __restrict__ bias,
               float* __restrict__ C, int M, int N, int K) {
  __shared__ alignas(16) __bf16 As[2][BM * BK];
  __shared__ alignas(16) __bf16 Bs[2][BN * BK];

  const int tid  = threadIdx.x;
  const int wave = tid >> 6;
  const int lane = tid & 63;
  const int wm = wave >> 2, wn = wave & 3;       // 2x4 waves; per-wave 128x64

  int bid = blockIdx.x, nwg = gridDim.x, swz = bid;
  if ((nwg & 7) == 0) swz = (bid & 7) * (nwg >> 3) + (bid >> 3);
  const int ntn = N / BN;
  const long row0 = (long)(swz / ntn) * BM;
  const long col0 = (long)(swz % ntn) * BN;

  const __bf16* Ag = A + row0 * (long)K;
  const __bf16* Bg = B + col0 * (long)K;

  // staging: chunk c = rows [c*64, c*64+64); wave-uniform LDS base; HW adds lane*16B
  const int srow = wave * 8 + (lane >> 3);            // row within chunk
  const int kswz = ((lane & 7) ^ (lane >> 3)) * 8;    // pre-swizzled k elems

#define STAGE_A(b, c, kt) gload_lds16(Ag + (long)((c)*64 + srow) * K + (kt) + kswz, \
                                      &As[b][(c)*4096 + wave*512])
#define STAGE_B(b, c, kt) gload_lds16(Bg + (long)((c)*64 + srow) * K + (kt) + kswz, \
                                      &Bs[b][(c)*4096 + wave*512])

  const int rsel = lane & 15;
  const int ksl  = lane >> 4;    // 0..3
  const int lan7 = lane & 7;     // == frag-row & 7 (bases are multiples of 16)

  f32x4  acc[8][4] = {};
  bf16x8 bf[4][2];               // B frags [n][kk], loaded each ph0, live all tile

#define PHASE(qq, bb, DO_B, STAGES, ENDW)                                        \
  {                                                                              \
    STAGES;                                                                      \
    bf16x8 af[2][2];                                                             \
    _Pragma("unroll")                                                            \
    for (int mi = 0; mi < 2; ++mi)                                               \
      _Pragma("unroll")                                                          \
      for (int kk = 0; kk < 2; ++kk)                                             \
        af[mi][kk] = *(const bf16x8*)&As[bb][(wm*128 + (2*(qq)+mi)*16 + rsel)*BK \
                                             + ((((kk<<2)+ksl) ^ lan7) << 3)];   \
    if (DO_B) {                                                                  \
      _Pragma("unroll")                                                          \
      for (int n = 0; n < 4; ++n)                                                \
        _Pragma("unroll")                                                        \
        for (int kk = 0; kk < 2; ++kk)                                           \
          bf[n][kk] = *(const bf16x8*)&Bs[bb][(wn*64 + n*16 + rsel)*BK           \
                                              + ((((kk<<2)+ksl) ^ lan7) << 3)];  \
    }                                                                            \
    __builtin_amdgcn_s_setprio(1);                                               \
    _Pragma("unroll")                                                            \
    for (int kk = 0; kk < 2; ++kk)                                               \
      _Pragma("unroll")                                                          \
      for (int mi = 0; mi < 2; ++mi)                                             \
        _Pragma("unroll")                                                        \
        for (int n = 0; n < 4; ++n)                                              \
          acc[2*(qq)+mi][n] = __builtin_amdgcn_mfma_f32_16x16x32_bf16(           \
              af[mi][kk], bf[n][kk], acc[2*(qq)+mi][n], 0, 0, 0);                \
    __builtin_amdgcn_s_setprio(0);                                               \
    ENDW;                                                                        \
    phase_barrier();                                                             \
  }

  const int NT = K / BK;   // >= 4 required

  // Prologue: tile0 full (8), tile1 partial (6: B0-3,A0,A2) — matches steady state.
  STAGE_B(0,0,0); STAGE_B(0,1,0); STAGE_B(0,2,0); STAGE_B(0,3,0);
  STAGE_A(0,0,0); STAGE_A(0,2,0); STAGE_A(0,1,0); STAGE_A(0,3,0);
  STAGE_B(1,0,BK); STAGE_B(1,1,BK); STAGE_B(1,2,BK); STAGE_B(1,3,BK);
  STAGE_A(1,0,BK); STAGE_A(1,2,BK);
  vmwait<6>();                         // tile0's 8 retired; tile1's 6 in flight
  phase_barrier();

  for (int t = 0; t < NT - 1; ++t) {   // t = 0 .. NT-2 (NT-2 = drain iter)
    const int b = t & 1;
    const long kt1 = (long)(t + 1) * BK;
    const long kt2 = (long)(t + 2) * BK;
    PHASE(0, b, 1, { STAGE_A(b^1, 1, kt1); STAGE_A(b^1, 3, kt1); }, (void)0)
    if (t <= NT - 3) {
      PHASE(1, b, 0, { STAGE_B(b, 0, kt2); STAGE_B(b, 1, kt2); }, (void)0)
      PHASE(2, b, 0, { STAGE_B(b, 2, kt2); STAGE_B(b, 3, kt2); STAGE_A(b, 0, kt2); }, (void)0)
      PHASE(3, b, 0, { STAGE_A(b, 2, kt2); }, vmwait<6>())
    } else {  // t == NT-2: nothing left to stage; drain all 8 in flight
      PHASE(1, b, 0, (void)0, (void)0)
      PHASE(2, b, 0, (void)0, (void)0)
      PHASE(3, b, 0, (void)0, vmwait<0>())
    }
  }
  {  // t = NT-1: no staging
    const int b = (NT - 1) & 1;
    PHASE(0, b, 1, (void)0, (void)0)
    PHASE(1, b, 0, (void)0, (void)0)
    PHASE(2, b, 0, (void)0, (void)0)
    PHASE(3, b, 0, (void)0, (void)0)
  }
#undef PHASE
#undef STAGE_A
#undef STAGE_B

  // Epilogue. C/D: col = lane&15, row = (lane>>4)*4 + j
  float sc[4], bv[4];
  #pragma unroll
  for (int n = 0; n < 4; ++n) {
    const long gcol = col0 + wn * 64 + n * 16 + rsel;
    sc[n] = scale[gcol];
    bv[n] = bias[gcol];
  }
  #pragma unroll
  for (int m = 0; m < 8; ++m) {
    const long grow = row0 + wm * 128 + m * 16 + ksl * 4;
    #pragma unroll
    for (int n = 0; n < 4; ++n) {
      const long gcol = col0 + wn * 64 + n * 16 + rsel;
      float* o = C + grow * (long)N + gcol;
      #pragma unroll
      for (int j = 0; j < 4; ++j)
        o[(long)j * N] = acc[m][n][j] * sc[n] + bv[n];
    }
  }
}

// ---- fallback (ws too small / odd shape): reg-staged 128x128, inline dequant ----
__global__ __launch_bounds__(256)
void qlin_gemm_small(const float* __restrict__ Af, const int* __restrict__ Bi,
                     const int* __restrict__ zp,
                     const float* __restrict__ scale, const float* __restrict__ bias,
                     float* __restrict__ C, int M, int N, int K) {
  __shared__ alignas(16) __bf16 As[128 * 64];
  __shared__ alignas(16) __bf16 Bs[128 * 64];
  const int tid = threadIdx.x, wave = tid >> 6, lane = tid & 63;
  int bid = blockIdx.x, nwg = gridDim.x, swz = bid;
  if ((nwg & 7) == 0) swz = (bid & 7) * (nwg >> 3) + (bid >> 3);
  const int ntn = N / 128;
  const long row0 = (long)(swz / ntn) * 128, col0 = (long)(swz % ntn) * 128;
  const int wr = wave >> 1, wc = wave & 1;
  f32x4 acc[4][4] = {};
  for (int kt = 0; kt < K; kt += 64) {
    #pragma unroll
    for (int i = 0; i < 4; ++i) {
      const int flat = i * 2048 + tid * 8;
      const int r = flat >> 6, cc = flat & 63;
      const int wcc = ((cc >> 3) ^ (r & 7)) << 3;
      const float* g = Af + (row0 + r) * (long)K + kt + cc;
      float4 f0 = *(const float4*)g; float4 f1 = *(const float4*)(g + 4);
      bf16x8 v;
      v[0]=(__bf16)f0.x; v[1]=(__bf16)f0.y; v[2]=(__bf16)f0.z; v[3]=(__bf16)f0.w;
      v[4]=(__bf16)f1.x; v[5]=(__bf16)f1.y; v[6]=(__bf16)f1.z; v[7]=(__bf16)f1.w;
      *(bf16x8*)(As + r * 64 + wcc) = v;
    }
    #pragma unroll
    for (int i = 0; i < 4; ++i) {
      const int flat = i * 2048 + tid * 8;
      const int r = flat >> 6, cc = flat & 63;
      const int wcc = ((cc >> 3) ^ (r & 7)) << 3;
      const long grow = col0 + r;
      const int z = zp[grow];
      const int* g = Bi + grow * (long)K + kt + cc;
      int4 a = *(const int4*)g; int4 b = *(const int4*)(g + 4);
      bf16x8 v;
      v[0]=(__bf16)(float)(a.x-z); v[1]=(__bf16)(float)(a.y-z);
      v[2]=(__bf16)(float)(a.z-z); v[3]=(__bf16)(float)(a.w-z);
      v[4]=(__bf16)(float)(b.x-z); v[5]=(__bf16)(float)(b.y-z);
      v[6]=(__bf16)(float)(b.z-z); v[7]=(__bf16)(float)(b.w-z);
      *(bf16x8*)(Bs + r * 64 + wcc) = v;
    }
    __syncthreads();
    #pragma unroll
    for (int kk = 0; kk < 2; ++kk) {
      bf16x8 af[4], bfr[4];
      const int rs = lane & 15, ks = kk * 4 + (lane >> 4);
      const int rd = (ks ^ (lane & 7)) << 3;
      #pragma unroll
      for (int m = 0; m < 4; ++m) af[m] = *(const bf16x8*)(As + (wr*64 + m*16 + rs)*64 + rd);
      #pragma unroll
      for (int n = 0; n < 4; ++n) bfr[n] = *(const bf16x8*)(Bs + (wc*64 + n*16 + rs)*64 + rd);
      #pragma unroll
      for (int m = 0; m < 4; ++m)
        #pragma unroll
        for (int n = 0; n < 4; ++n)
          acc[m][n] = __builtin_amdgcn_mfma_f32_16x16x32_bf16(af[m], bfr[n], acc[m][n], 0, 0, 0);
    }
    __syncthreads();
  }
  #pragma unroll
  for (int m = 0; m < 4; ++m) {
    const long grow = row0 + wr * 64 + m * 16 + ((lane >> 4) << 2);
    #pragma unroll
    for (int n = 0; n < 4; ++n) {
      const long gcol = col0 + wc * 64 + n * 16 + (lane & 15);
      const float s = scale[gcol], bb2 = bias[gcol];
      float* o = C + grow * (long)N + gcol;
      #pragma unroll
      for (int j = 0; j < 4; ++j) o[(long)j * N] = acc[m][n][j] * s + bb2;
    }
  }
}

extern "C" void kernel_launch(void* const* d_in, const int* in_sizes, int n_in,
                              void* d_out, int out_size, void* d_ws, size_t ws_size,
                              hipStream_t stream) {
  const float* x    = (const float*)d_in[0];
  const int*   wint = (const int*)d_in[1];
  const float* wsc  = (const float*)d_in[2];
  const int*   wzp  = (const int*)d_in[3];
  const float* bias = (const float*)d_in[4];
  float* out = (float*)d_out;

  const int N = in_sizes[4];            // 16384 (OUT)
  const int K = in_sizes[1] / N;        // 4096  (IN)
  const int M = in_sizes[0] / K;        // 8192  (B*S)

  const size_t xbytes = (size_t)M * K * sizeof(__bf16);
  const size_t wbytes = (size_t)N * K * sizeof(__bf16);

  if (ws_size >= xbytes + wbytes && (M % BM) == 0 && (N % BN) == 0 &&
      (K % BK) == 0 && K / BK >= 4) {
    __bf16* xb = (__bf16*)d_ws;
    __bf16* wb = (__bf16*)((char*)d_ws + xbytes);
    cvt_x_kernel<<<2048, 256, 0, stream>>>(x, xb, (long)M * K);
    cvt_w_kernel<<<2048, 256, 0, stream>>>(wint, wzp, wb, K, (long)N * K);
    const int grid = (M / BM) * (N / BN); // 32 * 64 = 2048
    qlin_gemm<<<grid, THREADS, 0, stream>>>(xb, wb, wsc, bias, out, M, N, K);
  } else {
    const int grid = (M / 128) * (N / 128);
    qlin_gemm_small<<<grid, 256, 0, stream>>>(x, wint, wzp, wsc, bias, out, M, N, K);
  }
}

// Round 6
// 1916.243 us; speedup vs baseline: 2.2486x; 2.2486x over previous
//
#include <hip/hip_runtime.h>
#include <hip/hip_bf16.h>

typedef __bf16 bf16x8 __attribute__((ext_vector_type(8)));
typedef float  f32x4  __attribute__((ext_vector_type(4)));

#define BM 256
#define BN 256
#define BK 64
#define THREADS 512

__device__ __forceinline__ void gload_lds16(const void* g, void* l) {
  __builtin_amdgcn_global_load_lds(
      (const __attribute__((address_space(1))) void*)g,
      (__attribute__((address_space(3))) void*)l, 16, 0, 0);
}

template<int N> __device__ __forceinline__ void vmwait() {
  if constexpr (N == 0)      asm volatile("s_waitcnt vmcnt(0)" ::: "memory");
  else if constexpr (N == 6) asm volatile("s_waitcnt vmcnt(6)" ::: "memory");
}
__device__ __forceinline__ void phase_barrier() {
  asm volatile("s_barrier" ::: "memory");
}

// ---- fp32 -> bf16 (RNE) ----
__global__ void cvt_x_kernel(const float* __restrict__ in, __bf16* __restrict__ out, long n) {
  long i0 = ((long)blockIdx.x * blockDim.x + threadIdx.x) * 8;
  long stride = (long)gridDim.x * blockDim.x * 8;
  for (long i = i0; i < n; i += stride) {
    float4 f0 = *(const float4*)(in + i);
    float4 f1 = *(const float4*)(in + i + 4);
    bf16x8 v;
    v[0] = (__bf16)f0.x; v[1] = (__bf16)f0.y; v[2] = (__bf16)f0.z; v[3] = (__bf16)f0.w;
    v[4] = (__bf16)f1.x; v[5] = (__bf16)f1.y; v[6] = (__bf16)f1.z; v[7] = (__bf16)f1.w;
    *(bf16x8*)(out + i) = v;
  }
}

// ---- (int32 weight - zp) -> bf16, EXACT for |v|<=255 ----
__global__ void cvt_w_kernel(const int* __restrict__ w, const int* __restrict__ zp,
                             __bf16* __restrict__ out, int K, long n) {
  long i0 = ((long)blockIdx.x * blockDim.x + threadIdx.x) * 8;
  long stride = (long)gridDim.x * blockDim.x * 8;
  for (long i = i0; i < n; i += stride) {
    int4 a = *(const int4*)(w + i);
    int4 b = *(const int4*)(w + i + 4);
    int z = zp[i / K];
    bf16x8 v;
    v[0] = (__bf16)(float)(a.x - z); v[1] = (__bf16)(float)(a.y - z);
    v[2] = (__bf16)(float)(a.z - z); v[3] = (__bf16)(float)(a.w - z);
    v[4] = (__bf16)(float)(b.x - z); v[5] = (__bf16)(float)(b.y - z);
    v[6] = (__bf16)(float)(b.z - z); v[7] = (__bf16)(float)(b.w - z);
    *(bf16x8*)(out + i) = v;
  }
}

// ============ 256x256 GEMM, 4 phases/K-tile, ONE barrier/phase ============
// Per phase: [stage issues] [frag ds_reads] [setprio+16 MFMA (compiler emits
// exact lgkmcnt)] [vmwait once per tile] [s_barrier w/ memory clobber].
// Stage batch for tile t+2 (buf b=t&1): ph1(t):B0,B1  ph2(t):B2,B3,A0
// ph3(t):A2  ph0(t+1):A1,A3.
// WAR: each region's write is >=1 barrier after its last read; reads complete
// pre-barrier (each ds_read feeds an MFMA in its own phase -> compiler lgkmcnt).
// RAW: at end-ph3(t) in-flight = 14 (8 of tile t+1 oldest, 6 of tile t+2);
// vmwait<6> retires tile t+1's batch exactly.
// IMPORTANT (round-5 lesson): the inner loop MUST be branch-free — a drain
// branch inside the loop caused accumulator spills (WRITE_SIZE 0.5->7.7 GB,
// 3x slowdown). Tail iterations NT-2 and NT-1 are fully peeled instead.
__global__ __launch_bounds__(THREADS, 2)
void qlin_gemm(const __bf16* __restrict__ A, const __bf16* __restrict__ B,
               const float* __restrict__ scale, const float* __restrict__ bias,
               float* __restrict__ C, int M, int N, int K) {
  __shared__ alignas(16) __bf16 As[2][BM * BK];
  __shared__ alignas(16) __bf16 Bs[2][BN * BK];

  const int tid  = threadIdx.x;
  const int wave = tid >> 6;
  const int lane = tid & 63;
  const int wm = wave >> 2, wn = wave & 3;       // 2x4 waves; per-wave 128x64

  int bid = blockIdx.x, nwg = gridDim.x, swz = bid;
  if ((nwg & 7) == 0) swz = (bid & 7) * (nwg >> 3) + (bid >> 3);
  const int ntn = N / BN;
  const long row0 = (long)(swz / ntn) * BM;
  const long col0 = (long)(swz % ntn) * BN;

  const __bf16* Ag = A + row0 * (long)K;
  const __bf16* Bg = B + col0 * (long)K;

  // staging: chunk c = rows [c*64, c*64+64); wave-uniform LDS base; HW adds lane*16B
  const int srow = wave * 8 + (lane >> 3);            // row within chunk
  const int kswz = ((lane & 7) ^ (lane >> 3)) * 8;    // pre-swizzled k elems

#define STAGE_A(b, c, kt) gload_lds16(Ag + (long)((c)*64 + srow) * K + (kt) + kswz, \
                                      &As[b][(c)*4096 + wave*512])
#define STAGE_B(b, c, kt) gload_lds16(Bg + (long)((c)*64 + srow) * K + (kt) + kswz, \
                                      &Bs[b][(c)*4096 + wave*512])

  const int rsel = lane & 15;
  const int ksl  = lane >> 4;    // 0..3
  const int lan7 = lane & 7;     // == frag-row & 7 (bases are multiples of 16)

  f32x4  acc[8][4] = {};
  bf16x8 bf[4][2];               // B frags [n][kk], loaded each ph0, live all tile

#define PHASE(qq, bb, DO_B, STAGES, ENDW)                                        \
  {                                                                              \
    STAGES;                                                                      \
    bf16x8 af[2][2];                                                             \
    _Pragma("unroll")                                                            \
    for (int mi = 0; mi < 2; ++mi)                                               \
      _Pragma("unroll")                                                          \
      for (int kk = 0; kk < 2; ++kk)                                             \
        af[mi][kk] = *(const bf16x8*)&As[bb][(wm*128 + (2*(qq)+mi)*16 + rsel)*BK \
                                             + ((((kk<<2)+ksl) ^ lan7) << 3)];   \
    if (DO_B) {                                                                  \
      _Pragma("unroll")                                                          \
      for (int n = 0; n < 4; ++n)                                                \
        _Pragma("unroll")                                                        \
        for (int kk = 0; kk < 2; ++kk)                                           \
          bf[n][kk] = *(const bf16x8*)&Bs[bb][(wn*64 + n*16 + rsel)*BK           \
                                              + ((((kk<<2)+ksl) ^ lan7) << 3)];  \
    }                                                                            \
    __builtin_amdgcn_s_setprio(1);                                               \
    _Pragma("unroll")                                                            \
    for (int kk = 0; kk < 2; ++kk)                                               \
      _Pragma("unroll")                                                          \
      for (int mi = 0; mi < 2; ++mi)                                             \
        _Pragma("unroll")                                                        \
        for (int n = 0; n < 4; ++n)                                              \
          acc[2*(qq)+mi][n] = __builtin_amdgcn_mfma_f32_16x16x32_bf16(           \
              af[mi][kk], bf[n][kk], acc[2*(qq)+mi][n], 0, 0, 0);                \
    __builtin_amdgcn_s_setprio(0);                                               \
    ENDW;                                                                        \
    phase_barrier();                                                             \
  }

  const int NT = K / BK;   // >= 4 required

  // Prologue: tile0 full (8), tile1 partial (6: B0-3,A0,A2) — matches steady state.
  STAGE_B(0,0,0); STAGE_B(0,1,0); STAGE_B(0,2,0); STAGE_B(0,3,0);
  STAGE_A(0,0,0); STAGE_A(0,2,0); STAGE_A(0,1,0); STAGE_A(0,3,0);
  STAGE_B(1,0,BK); STAGE_B(1,1,BK); STAGE_B(1,2,BK); STAGE_B(1,3,BK);
  STAGE_A(1,0,BK); STAGE_A(1,2,BK);
  vmwait<6>();                         // tile0's 8 retired; tile1's 6 in flight
  phase_barrier();

  // Steady loop: branch-free. t = 0 .. NT-3.
  for (int t = 0; t < NT - 2; ++t) {
    const int b = t & 1;
    const long kt1 = (long)(t + 1) * BK;
    const long kt2 = (long)(t + 2) * BK;
    PHASE(0, b, 1, { STAGE_A(b^1, 1, kt1); STAGE_A(b^1, 3, kt1); }, (void)0)
    PHASE(1, b, 0, { STAGE_B(b, 0, kt2); STAGE_B(b, 1, kt2); }, (void)0)
    PHASE(2, b, 0, { STAGE_B(b, 2, kt2); STAGE_B(b, 3, kt2); STAGE_A(b, 0, kt2); }, (void)0)
    PHASE(3, b, 0, { STAGE_A(b, 2, kt2); }, vmwait<6>())
  }
  {  // t = NT-2 (peeled): finish staging tile NT-1 (A1,A3), then drain all 8.
    const int b = (NT - 2) & 1;
    const long kt1 = (long)(NT - 1) * BK;
    PHASE(0, b, 1, { STAGE_A(b^1, 1, kt1); STAGE_A(b^1, 3, kt1); }, (void)0)
    PHASE(1, b, 0, (void)0, (void)0)
    PHASE(2, b, 0, (void)0, (void)0)
    PHASE(3, b, 0, (void)0, vmwait<0>())
  }
  {  // t = NT-1 (peeled): pure compute.
    const int b = (NT - 1) & 1;
    PHASE(0, b, 1, (void)0, (void)0)
    PHASE(1, b, 0, (void)0, (void)0)
    PHASE(2, b, 0, (void)0, (void)0)
    PHASE(3, b, 0, (void)0, (void)0)
  }
#undef PHASE
#undef STAGE_A
#undef STAGE_B

  // Epilogue. C/D: col = lane&15, row = (lane>>4)*4 + j
  float sc[4], bv[4];
  #pragma unroll
  for (int n = 0; n < 4; ++n) {
    const long gcol = col0 + wn * 64 + n * 16 + rsel;
    sc[n] = scale[gcol];
    bv[n] = bias[gcol];
  }
  #pragma unroll
  for (int m = 0; m < 8; ++m) {
    const long grow = row0 + wm * 128 + m * 16 + ksl * 4;
    #pragma unroll
    for (int n = 0; n < 4; ++n) {
      const long gcol = col0 + wn * 64 + n * 16 + rsel;
      float* o = C + grow * (long)N + gcol;
      #pragma unroll
      for (int j = 0; j < 4; ++j)
        o[(long)j * N] = acc[m][n][j] * sc[n] + bv[n];
    }
  }
}

// ---- fallback (ws too small / odd shape): reg-staged 128x128, inline dequant ----
__global__ __launch_bounds__(256)
void qlin_gemm_small(const float* __restrict__ Af, const int* __restrict__ Bi,
                     const int* __restrict__ zp,
                     const float* __restrict__ scale, const float* __restrict__ bias,
                     float* __restrict__ C, int M, int N, int K) {
  __shared__ alignas(16) __bf16 As[128 * 64];
  __shared__ alignas(16) __bf16 Bs[128 * 64];
  const int tid = threadIdx.x, wave = tid >> 6, lane = tid & 63;
  int bid = blockIdx.x, nwg = gridDim.x, swz = bid;
  if ((nwg & 7) == 0) swz = (bid & 7) * (nwg >> 3) + (bid >> 3);
  const int ntn = N / 128;
  const long row0 = (long)(swz / ntn) * 128, col0 = (long)(swz % ntn) * 128;
  const int wr = wave >> 1, wc = wave & 1;
  f32x4 acc[4][4] = {};
  for (int kt = 0; kt < K; kt += 64) {
    #pragma unroll
    for (int i = 0; i < 4; ++i) {
      const int flat = i * 2048 + tid * 8;
      const int r = flat >> 6, cc = flat & 63;
      const int wcc = ((cc >> 3) ^ (r & 7)) << 3;
      const float* g = Af + (row0 + r) * (long)K + kt + cc;
      float4 f0 = *(const float4*)g; float4 f1 = *(const float4*)(g + 4);
      bf16x8 v;
      v[0]=(__bf16)f0.x; v[1]=(__bf16)f0.y; v[2]=(__bf16)f0.z; v[3]=(__bf16)f0.w;
      v[4]=(__bf16)f1.x; v[5]=(__bf16)f1.y; v[6]=(__bf16)f1.z; v[7]=(__bf16)f1.w;
      *(bf16x8*)(As + r * 64 + wcc) = v;
    }
    #pragma unroll
    for (int i = 0; i < 4; ++i) {
      const int flat = i * 2048 + tid * 8;
      const int r = flat >> 6, cc = flat & 63;
      const int wcc = ((cc >> 3) ^ (r & 7)) << 3;
      const long grow = col0 + r;
      const int z = zp[grow];
      const int* g = Bi + grow * (long)K + kt + cc;
      int4 a = *(const int4*)g; int4 b = *(const int4*)(g + 4);
      bf16x8 v;
      v[0]=(__bf16)(float)(a.x-z); v[1]=(__bf16)(float)(a.y-z);
      v[2]=(__bf16)(float)(a.z-z); v[3]=(__bf16)(float)(a.w-z);
      v[4]=(__bf16)(float)(b.x-z); v[5]=(__bf16)(float)(b.y-z);
      v[6]=(__bf16)(float)(b.z-z); v[7]=(__bf16)(float)(b.w-z);
      *(bf16x8*)(Bs + r * 64 + wcc) = v;
    }
    __syncthreads();
    #pragma unroll
    for (int kk = 0; kk < 2; ++kk) {
      bf16x8 af[4], bfr[4];
      const int rs = lane & 15, ks = kk * 4 + (lane >> 4);
      const int rd = (ks ^ (lane & 7)) << 3;
      #pragma unroll
      for (int m = 0; m < 4; ++m) af[m] = *(const bf16x8*)(As + (wr*64 + m*16 + rs)*64 + rd);
      #pragma unroll
      for (int n = 0; n < 4; ++n) bfr[n] = *(const bf16x8*)(Bs + (wc*64 + n*16 + rs)*64 + rd);
      #pragma unroll
      for (int m = 0; m < 4; ++m)
        #pragma unroll
        for (int n = 0; n < 4; ++n)
          acc[m][n] = __builtin_amdgcn_mfma_f32_16x16x32_bf16(af[m], bfr[n], acc[m][n], 0, 0, 0);
    }
    __syncthreads();
  }
  #pragma unroll
  for (int m = 0; m < 4; ++m) {
    const long grow = row0 + wr * 64 + m * 16 + ((lane >> 4) << 2);
    #pragma unroll
    for (int n = 0; n < 4; ++n) {
      const long gcol = col0 + wc * 64 + n * 16 + (lane & 15);
      const float s = scale[gcol], bb2 = bias[gcol];
      float* o = C + grow * (long)N + gcol;
      #pragma unroll
      for (int j = 0; j < 4; ++j) o[(long)j * N] = acc[m][n][j] * s + bb2;
    }
  }
}

extern "C" void kernel_launch(void* const* d_in, const int* in_sizes, int n_in,
                              void* d_out, int out_size, void* d_ws, size_t ws_size,
                              hipStream_t stream) {
  const float* x    = (const float*)d_in[0];
  const int*   wint = (const int*)d_in[1];
  const float* wsc  = (const float*)d_in[2];
  const int*   wzp  = (const int*)d_in[3];
  const float* bias = (const float*)d_in[4];
  float* out = (float*)d_out;

  const int N = in_sizes[4];            // 16384 (OUT)
  const int K = in_sizes[1] / N;        // 4096  (IN)
  const int M = in_sizes[0] / K;        // 8192  (B*S)

  const size_t xbytes = (size_t)M * K * sizeof(__bf16);
  const size_t wbytes = (size_t)N * K * sizeof(__bf16);

  if (ws_size >= xbytes + wbytes && (M % BM) == 0 && (N % BN) == 0 &&
      (K % BK) == 0 && K / BK >= 4) {
    __bf16* xb = (__bf16*)d_ws;
    __bf16* wb = (__bf16*)((char*)d_ws + xbytes);
    cvt_x_kernel<<<2048, 256, 0, stream>>>(x, xb, (long)M * K);
    cvt_w_kernel<<<2048, 256, 0, stream>>>(wint, wzp, wb, K, (long)N * K);
    const int grid = (M / BM) * (N / BN); // 32 * 64 = 2048
    qlin_gemm<<<grid, THREADS, 0, stream>>>(xb, wb, wsc, bias, out, M, N, K);
  } else {
    const int grid = (M / 128) * (N / 128);
    qlin_gemm_small<<<grid, 256, 0, stream>>>(x, wint, wzp, wsc, bias, out, M, N, K);
  }
}

// Round 7
// 1434.066 us; speedup vs baseline: 3.0047x; 1.3362x over previous
//
#include <hip/hip_runtime.h>
#include <hip/hip_bf16.h>

typedef __bf16 bf16x8 __attribute__((ext_vector_type(8)));
typedef float  f32x4  __attribute__((ext_vector_type(4)));

#define BM 256
#define BN 256
#define BK 64
#define THREADS 512

__device__ __forceinline__ void gload_lds16(const void* g, void* l) {
  __builtin_amdgcn_global_load_lds(
      (const __attribute__((address_space(1))) void*)g,
      (__attribute__((address_space(3))) void*)l, 16, 0, 0);
}

// Bare waitcnts — NO ":::memory" clobber. A memory-clobbered asm is marked
// mayLoad/mayStore and forces SIInsertWaitcnts to emit a conservative
// vmcnt(0) drain before it (outstanding global_load_lds writes could alias) —
// which defeats the counted-vmcnt pipeline entirely (rounds 2-6 pathology).
template<int N> __device__ __forceinline__ void vmwait() {
  if constexpr (N == 0)      asm volatile("s_waitcnt vmcnt(0)");
  else if constexpr (N == 6) asm volatile("s_waitcnt vmcnt(6)");
}

// ---- fp32 -> bf16 (RNE) ----
__global__ void cvt_x_kernel(const float* __restrict__ in, __bf16* __restrict__ out, long n) {
  long i0 = ((long)blockIdx.x * blockDim.x + threadIdx.x) * 8;
  long stride = (long)gridDim.x * blockDim.x * 8;
  for (long i = i0; i < n; i += stride) {
    float4 f0 = *(const float4*)(in + i);
    float4 f1 = *(const float4*)(in + i + 4);
    bf16x8 v;
    v[0] = (__bf16)f0.x; v[1] = (__bf16)f0.y; v[2] = (__bf16)f0.z; v[3] = (__bf16)f0.w;
    v[4] = (__bf16)f1.x; v[5] = (__bf16)f1.y; v[6] = (__bf16)f1.z; v[7] = (__bf16)f1.w;
    *(bf16x8*)(out + i) = v;
  }
}

// ---- (int32 weight - zp) -> bf16, EXACT for |v|<=255 ----
__global__ void cvt_w_kernel(const int* __restrict__ w, const int* __restrict__ zp,
                             __bf16* __restrict__ out, int K, long n) {
  long i0 = ((long)blockIdx.x * blockDim.x + threadIdx.x) * 8;
  long stride = (long)gridDim.x * blockDim.x * 8;
  for (long i = i0; i < n; i += stride) {
    int4 a = *(const int4*)(w + i);
    int4 b = *(const int4*)(w + i + 4);
    int z = zp[i / K];
    bf16x8 v;
    v[0] = (__bf16)(float)(a.x - z); v[1] = (__bf16)(float)(a.y - z);
    v[2] = (__bf16)(float)(a.z - z); v[3] = (__bf16)(float)(a.w - z);
    v[4] = (__bf16)(float)(b.x - z); v[5] = (__bf16)(float)(b.y - z);
    v[6] = (__bf16)(float)(b.z - z); v[7] = (__bf16)(float)(b.w - z);
    *(bf16x8*)(out + i) = v;
  }
}

// ============ 256x256 GEMM, 4 phases/K-tile, 2 barriers/phase ============
// m201-template skeleton with clean sync primitives:
//   [frag ds_reads (C++)] [stage gload_lds issues] s_barrier(builtin)
//   setprio(1) [16 MFMA — compiler inserts precise lgkmcnt] setprio(0)
//   [vmwait<N> bare asm, ph3 only] s_barrier(builtin)
// Stage batch for tile t+2 (buf b=t&1): ph1:B0,B1  ph2:B2,B3,A0  ph3:A2
// ph0(t+1):A1,A3.
// WAR: reads(p) complete before their MFMA (compiler lgkmcnt) which precedes
// the end-of-phase barrier; any stage into that region is issued >=1 barrier
// later. RAW: at end-ph3(t) in-flight = 14 (tile t+1's 8 oldest + t+2's 6);
// vmwait<6> retires tile t+1's batch exactly, then barrier publishes.
// Inner loop branch-free; tails NT-2, NT-1 fully peeled (round-5 spill lesson).
__global__ __launch_bounds__(THREADS, 2)
void qlin_gemm(const __bf16* __restrict__ A, const __bf16* __restrict__ B,
               const float* __restrict__ scale, const float* __restrict__ bias,
               float* __restrict__ C, int M, int N, int K) {
  __shared__ alignas(16) __bf16 As[2][BM * BK];
  __shared__ alignas(16) __bf16 Bs[2][BN * BK];

  const int tid  = threadIdx.x;
  const int wave = tid >> 6;
  const int lane = tid & 63;
  const int wm = wave >> 2, wn = wave & 3;       // 2x4 waves; per-wave 128x64

  int bid = blockIdx.x, nwg = gridDim.x, swz = bid;
  if ((nwg & 7) == 0) swz = (bid & 7) * (nwg >> 3) + (bid >> 3);
  const int ntn = N / BN;
  const long row0 = (long)(swz / ntn) * BM;
  const long col0 = (long)(swz % ntn) * BN;

  const __bf16* Ag = A + row0 * (long)K;
  const __bf16* Bg = B + col0 * (long)K;

  // staging: chunk c = rows [c*64, c*64+64); wave-uniform LDS base; HW adds lane*16B
  const int srow = wave * 8 + (lane >> 3);            // row within chunk
  const int kswz = ((lane & 7) ^ (lane >> 3)) * 8;    // pre-swizzled k elems

#define STAGE_A(b, c, kt) gload_lds16(Ag + (long)((c)*64 + srow) * K + (kt) + kswz, \
                                      &As[b][(c)*4096 + wave*512])
#define STAGE_B(b, c, kt) gload_lds16(Bg + (long)((c)*64 + srow) * K + (kt) + kswz, \
                                      &Bs[b][(c)*4096 + wave*512])

  const int rsel = lane & 15;
  const int ksl  = lane >> 4;    // 0..3
  const int lan7 = lane & 7;     // == frag-row & 7 (bases are multiples of 16)

  f32x4  acc[8][4] = {};
  bf16x8 bf[4][2];               // B frags [n][kk], loaded each ph0, live all tile

#define PHASE(qq, bb, DO_B, STAGES, ENDW)                                        \
  {                                                                              \
    bf16x8 af[2][2];                                                             \
    _Pragma("unroll")                                                            \
    for (int mi = 0; mi < 2; ++mi)                                               \
      _Pragma("unroll")                                                          \
      for (int kk = 0; kk < 2; ++kk)                                             \
        af[mi][kk] = *(const bf16x8*)&As[bb][(wm*128 + (2*(qq)+mi)*16 + rsel)*BK \
                                             + ((((kk<<2)+ksl) ^ lan7) << 3)];   \
    if (DO_B) {                                                                  \
      _Pragma("unroll")                                                          \
      for (int n = 0; n < 4; ++n)                                                \
        _Pragma("unroll")                                                        \
        for (int kk = 0; kk < 2; ++kk)                                           \
          bf[n][kk] = *(const bf16x8*)&Bs[bb][(wn*64 + n*16 + rsel)*BK           \
                                              + ((((kk<<2)+ksl) ^ lan7) << 3)];  \
    }                                                                            \
    STAGES;                                                                      \
    __builtin_amdgcn_s_barrier();                                                \
    __builtin_amdgcn_s_setprio(1);                                               \
    _Pragma("unroll")                                                            \
    for (int kk = 0; kk < 2; ++kk)                                               \
      _Pragma("unroll")                                                          \
      for (int mi = 0; mi < 2; ++mi)                                             \
        _Pragma("unroll")                                                        \
        for (int n = 0; n < 4; ++n)                                              \
          acc[2*(qq)+mi][n] = __builtin_amdgcn_mfma_f32_16x16x32_bf16(           \
              af[mi][kk], bf[n][kk], acc[2*(qq)+mi][n], 0, 0, 0);                \
    __builtin_amdgcn_s_setprio(0);                                               \
    ENDW;                                                                        \
    __builtin_amdgcn_s_barrier();                                                \
  }

  const int NT = K / BK;   // >= 4 required

  // Prologue: tile0 full (8), tile1 partial (6: B0-3,A0,A2) — matches steady state.
  STAGE_B(0,0,0); STAGE_B(0,1,0); STAGE_B(0,2,0); STAGE_B(0,3,0);
  STAGE_A(0,0,0); STAGE_A(0,2,0); STAGE_A(0,1,0); STAGE_A(0,3,0);
  STAGE_B(1,0,BK); STAGE_B(1,1,BK); STAGE_B(1,2,BK); STAGE_B(1,3,BK);
  STAGE_A(1,0,BK); STAGE_A(1,2,BK);
  vmwait<6>();                         // tile0's 8 retired; tile1's 6 in flight
  __builtin_amdgcn_s_barrier();

  // Steady loop: branch-free. t = 0 .. NT-3.
  for (int t = 0; t < NT - 2; ++t) {
    const int b = t & 1;
    const long kt1 = (long)(t + 1) * BK;
    const long kt2 = (long)(t + 2) * BK;
    PHASE(0, b, 1, { STAGE_A(b^1, 1, kt1); STAGE_A(b^1, 3, kt1); }, (void)0)
    PHASE(1, b, 0, { STAGE_B(b, 0, kt2); STAGE_B(b, 1, kt2); }, (void)0)
    PHASE(2, b, 0, { STAGE_B(b, 2, kt2); STAGE_B(b, 3, kt2); STAGE_A(b, 0, kt2); }, (void)0)
    PHASE(3, b, 0, { STAGE_A(b, 2, kt2); }, vmwait<6>())
  }
  {  // t = NT-2 (peeled): finish staging tile NT-1 (A1,A3), then drain all 8.
    const int b = (NT - 2) & 1;
    const long kt1 = (long)(NT - 1) * BK;
    PHASE(0, b, 1, { STAGE_A(b^1, 1, kt1); STAGE_A(b^1, 3, kt1); }, (void)0)
    PHASE(1, b, 0, (void)0, (void)0)
    PHASE(2, b, 0, (void)0, (void)0)
    PHASE(3, b, 0, (void)0, vmwait<0>())
  }
  {  // t = NT-1 (peeled): pure compute.
    const int b = (NT - 1) & 1;
    PHASE(0, b, 1, (void)0, (void)0)
    PHASE(1, b, 0, (void)0, (void)0)
    PHASE(2, b, 0, (void)0, (void)0)
    PHASE(3, b, 0, (void)0, (void)0)
  }
#undef PHASE
#undef STAGE_A
#undef STAGE_B

  // Epilogue. C/D: col = lane&15, row = (lane>>4)*4 + j
  float sc[4], bv[4];
  #pragma unroll
  for (int n = 0; n < 4; ++n) {
    const long gcol = col0 + wn * 64 + n * 16 + rsel;
    sc[n] = scale[gcol];
    bv[n] = bias[gcol];
  }
  #pragma unroll
  for (int m = 0; m < 8; ++m) {
    const long grow = row0 + wm * 128 + m * 16 + ksl * 4;
    #pragma unroll
    for (int n = 0; n < 4; ++n) {
      const long gcol = col0 + wn * 64 + n * 16 + rsel;
      float* o = C + grow * (long)N + gcol;
      #pragma unroll
      for (int j = 0; j < 4; ++j)
        o[(long)j * N] = acc[m][n][j] * sc[n] + bv[n];
    }
  }
}

// ---- fallback (ws too small / odd shape): reg-staged 128x128, inline dequant ----
__global__ __launch_bounds__(256)
void qlin_gemm_small(const float* __restrict__ Af, const int* __restrict__ Bi,
                     const int* __restrict__ zp,
                     const float* __restrict__ scale, const float* __restrict__ bias,
                     float* __restrict__ C, int M, int N, int K) {
  __shared__ alignas(16) __bf16 As[128 * 64];
  __shared__ alignas(16) __bf16 Bs[128 * 64];
  const int tid = threadIdx.x, wave = tid >> 6, lane = tid & 63;
  int bid = blockIdx.x, nwg = gridDim.x, swz = bid;
  if ((nwg & 7) == 0) swz = (bid & 7) * (nwg >> 3) + (bid >> 3);
  const int ntn = N / 128;
  const long row0 = (long)(swz / ntn) * 128, col0 = (long)(swz % ntn) * 128;
  const int wr = wave >> 1, wc = wave & 1;
  f32x4 acc[4][4] = {};
  for (int kt = 0; kt < K; kt += 64) {
    #pragma unroll
    for (int i = 0; i < 4; ++i) {
      const int flat = i * 2048 + tid * 8;
      const int r = flat >> 6, cc = flat & 63;
      const int wcc = ((cc >> 3) ^ (r & 7)) << 3;
      const float* g = Af + (row0 + r) * (long)K + kt + cc;
      float4 f0 = *(const float4*)g; float4 f1 = *(const float4*)(g + 4);
      bf16x8 v;
      v[0]=(__bf16)f0.x; v[1]=(__bf16)f0.y; v[2]=(__bf16)f0.z; v[3]=(__bf16)f0.w;
      v[4]=(__bf16)f1.x; v[5]=(__bf16)f1.y; v[6]=(__bf16)f1.z; v[7]=(__bf16)f1.w;
      *(bf16x8*)(As + r * 64 + wcc) = v;
    }
    #pragma unroll
    for (int i = 0; i < 4; ++i) {
      const int flat = i * 2048 + tid * 8;
      const int r = flat >> 6, cc = flat & 63;
      const int wcc = ((cc >> 3) ^ (r & 7)) << 3;
      const long grow = col0 + r;
      const int z = zp[grow];
      const int* g = Bi + grow * (long)K + kt + cc;
      int4 a = *(const int4*)g; int4 b = *(const int4*)(g + 4);
      bf16x8 v;
      v[0]=(__bf16)(float)(a.x-z); v[1]=(__bf16)(float)(a.y-z);
      v[2]=(__bf16)(float)(a.z-z); v[3]=(__bf16)(float)(a.w-z);
      v[4]=(__bf16)(float)(b.x-z); v[5]=(__bf16)(float)(b.y-z);
      v[6]=(__bf16)(float)(b.z-z); v[7]=(__bf16)(float)(b.w-z);
      *(bf16x8*)(Bs + r * 64 + wcc) = v;
    }
    __syncthreads();
    #pragma unroll
    for (int kk = 0; kk < 2; ++kk) {
      bf16x8 af[4], bfr[4];
      const int rs = lane & 15, ks = kk * 4 + (lane >> 4);
      const int rd = (ks ^ (lane & 7)) << 3;
      #pragma unroll
      for (int m = 0; m < 4; ++m) af[m] = *(const bf16x8*)(As + (wr*64 + m*16 + rs)*64 + rd);
      #pragma unroll
      for (int n = 0; n < 4; ++n) bfr[n] = *(const bf16x8*)(Bs + (wc*64 + n*16 + rs)*64 + rd);
      #pragma unroll
      for (int m = 0; m < 4; ++m)
        #pragma unroll
        for (int n = 0; n < 4; ++n)
          acc[m][n] = __builtin_amdgcn_mfma_f32_16x16x32_bf16(af[m], bfr[n], acc[m][n], 0, 0, 0);
    }
    __syncthreads();
  }
  #pragma unroll
  for (int m = 0; m < 4; ++m) {
    const long grow = row0 + wr * 64 + m * 16 + ((lane >> 4) << 2);
    #pragma unroll
    for (int n = 0; n < 4; ++n) {
      const long gcol = col0 + wc * 64 + n * 16 + (lane & 15);
      const float s = scale[gcol], bb2 = bias[gcol];
      float* o = C + grow * (long)N + gcol;
      #pragma unroll
      for (int j = 0; j < 4; ++j) o[(long)j * N] = acc[m][n][j] * s + bb2;
    }
  }
}

extern "C" void kernel_launch(void* const* d_in, const int* in_sizes, int n_in,
                              void* d_out, int out_size, void* d_ws, size_t ws_size,
                              hipStream_t stream) {
  const float* x    = (const float*)d_in[0];
  const int*   wint = (const int*)d_in[1];
  const float* wsc  = (const float*)d_in[2];
  const int*   wzp  = (const int*)d_in[3];
  const float* bias = (const float*)d_in[4];
  float* out = (float*)d_out;

  const int N = in_sizes[4];            // 16384 (OUT)
  const int K = in_sizes[1] / N;        // 4096  (IN)
  const int M = in_sizes[0] / K;        // 8192  (B*S)

  const size_t xbytes = (size_t)M * K * sizeof(__bf16);
  const size_t wbytes = (size_t)N * K * sizeof(__bf16);

  if (ws_size >= xbytes + wbytes && (M % BM) == 0 && (N % BN) == 0 &&
      (K % BK) == 0 && K / BK >= 4) {
    __bf16* xb = (__bf16*)d_ws;
    __bf16* wb = (__bf16*)((char*)d_ws + xbytes);
    cvt_x_kernel<<<2048, 256, 0, stream>>>(x, xb, (long)M * K);
    cvt_w_kernel<<<2048, 256, 0, stream>>>(wint, wzp, wb, K, (long)N * K);
    const int grid = (M / BM) * (N / BN); // 32 * 64 = 2048
    qlin_gemm<<<grid, THREADS, 0, stream>>>(xb, wb, wsc, bias, out, M, N, K);
  } else {
    const int grid = (M / 128) * (N / 128);
    qlin_gemm_small<<<grid, 256, 0, stream>>>(x, wint, wzp, wsc, bias, out, M, N, K);
  }
}

// Round 8
// 1355.819 us; speedup vs baseline: 3.1781x; 1.0577x over previous
//
#include <hip/hip_runtime.h>
#include <hip/hip_bf16.h>

typedef __bf16 bf16x8 __attribute__((ext_vector_type(8)));
typedef float  f32x4  __attribute__((ext_vector_type(4)));

#define BM 256
#define BN 256
#define BK 64
#define THREADS 512

__device__ __forceinline__ void gload_lds16(const void* g, void* l) {
  __builtin_amdgcn_global_load_lds(
      (const __attribute__((address_space(1))) void*)g,
      (__attribute__((address_space(3))) void*)l, 16, 0, 0);
}

// Bare waitcnts — NO ":::memory" clobber (round-6 lesson: clobber forces a
// conservative vmcnt(0) drain).
template<int N> __device__ __forceinline__ void vmwait() {
  if constexpr (N == 0)      asm volatile("s_waitcnt vmcnt(0)");
  else if constexpr (N == 6) asm volatile("s_waitcnt vmcnt(6)");
}
__device__ __forceinline__ void lgkm0() { asm volatile("s_waitcnt lgkmcnt(0)"); }
__device__ __forceinline__ void lgkm8() { asm volatile("s_waitcnt lgkmcnt(8)"); }

// ---- fp32 -> bf16 (RNE) ----
__global__ void cvt_x_kernel(const float* __restrict__ in, __bf16* __restrict__ out, long n) {
  long i0 = ((long)blockIdx.x * blockDim.x + threadIdx.x) * 8;
  long stride = (long)gridDim.x * blockDim.x * 8;
  for (long i = i0; i < n; i += stride) {
    float4 f0 = *(const float4*)(in + i);
    float4 f1 = *(const float4*)(in + i + 4);
    bf16x8 v;
    v[0] = (__bf16)f0.x; v[1] = (__bf16)f0.y; v[2] = (__bf16)f0.z; v[3] = (__bf16)f0.w;
    v[4] = (__bf16)f1.x; v[5] = (__bf16)f1.y; v[6] = (__bf16)f1.z; v[7] = (__bf16)f1.w;
    *(bf16x8*)(out + i) = v;
  }
}

// ---- (int32 weight - zp) -> bf16, EXACT for |v|<=255 ----
__global__ void cvt_w_kernel(const int* __restrict__ w, const int* __restrict__ zp,
                             __bf16* __restrict__ out, int K, long n) {
  long i0 = ((long)blockIdx.x * blockDim.x + threadIdx.x) * 8;
  long stride = (long)gridDim.x * blockDim.x * 8;
  for (long i = i0; i < n; i += stride) {
    int4 a = *(const int4*)(w + i);
    int4 b = *(const int4*)(w + i + 4);
    int z = zp[i / K];
    bf16x8 v;
    v[0] = (__bf16)(float)(a.x - z); v[1] = (__bf16)(float)(a.y - z);
    v[2] = (__bf16)(float)(a.z - z); v[3] = (__bf16)(float)(a.w - z);
    v[4] = (__bf16)(float)(b.x - z); v[5] = (__bf16)(float)(b.y - z);
    v[6] = (__bf16)(float)(b.z - z); v[7] = (__bf16)(float)(b.w - z);
    *(bf16x8*)(out + i) = v;
  }
}

// ========= 256x256 GEMM, faithful m201-style 8-phase (2 K-tiles/iter) =========
// Iteration = tiles (t, t+1) from LITERAL bufs (0,1) -> all LDS addresses are
// compile-time constants (round-7 lesson: runtime buf index = per-phase VALU
// address work between barriers).
// Phase = { 4 af ds_reads (+8 bf in P0) ; 2 gload_lds stages ; [lgkmcnt(8) if
// 12-read] ; s_barrier ; lgkmcnt(0) ; setprio(1) ; 16 MFMA ; setprio(0) ;
// [vmcnt(6) at P3] ; s_barrier }.
// Stage schedule (uniform 2/phase), during tile t (buf b): P0: A1,A3(t+1->b^1)
// P1: B0,B1(t+2->b)  P2: B2,B3(t+2->b)  P3: A0,A2(t+2->b).
// WAR margins: B(b) last read P0, staged P1+ (>=1 barrier). A chunks 0,2 last
// read ph1 (quadrants 0-1), staged P3 (>=2 barriers). A chunks 1,3 last read
// ph3, staged next-P0 (>=1 barrier). All reads complete pre-barrier (each
// feeds an MFMA in its own phase).
// RAW: at end-P3(t), outstanding = t+1's 8 oldest + t+2's 6; vmcnt(6) retires
// exactly tile t+1 (incl. its A1,A3 issued at t's P0).
// Inner loop branch-free; tail pair (NT-2, NT-1) fully peeled (round-5 lesson:
// in-loop drain branch spilled acc -> 3x slowdown).
__global__ __launch_bounds__(THREADS, 2)
void qlin_gemm(const __bf16* __restrict__ A, const __bf16* __restrict__ B,
               const float* __restrict__ scale, const float* __restrict__ bias,
               float* __restrict__ C, int M, int N, int K) {
  __shared__ alignas(16) __bf16 As[2][BM * BK];
  __shared__ alignas(16) __bf16 Bs[2][BN * BK];

  const int tid  = threadIdx.x;
  const int wave = tid >> 6;
  const int lane = tid & 63;
  const int wm = wave >> 2, wn = wave & 3;       // 2x4 waves; per-wave 128x64

  int bid = blockIdx.x, nwg = gridDim.x, swz = bid;
  if ((nwg & 7) == 0) swz = (bid & 7) * (nwg >> 3) + (bid >> 3);
  const int ntn = N / BN;
  const long row0 = (long)(swz / ntn) * BM;
  const long col0 = (long)(swz % ntn) * BN;

  const __bf16* Ag = A + row0 * (long)K;
  const __bf16* Bg = B + col0 * (long)K;

  // staging: chunk c = rows [c*64, c*64+64); wave-uniform LDS base; HW adds lane*16B
  const int srow = wave * 8 + (lane >> 3);            // row within chunk
  const int kswz = ((lane & 7) ^ (lane >> 3)) * 8;    // pre-swizzled k elems

#define STAGE_A(b, c, kt) gload_lds16(Ag + (long)((c)*64 + srow) * K + (kt) + kswz, \
                                      &As[b][(c)*4096 + wave*512])
#define STAGE_B(b, c, kt) gload_lds16(Bg + (long)((c)*64 + srow) * K + (kt) + kswz, \
                                      &Bs[b][(c)*4096 + wave*512])

  const int rsel = lane & 15;
  const int ksl  = lane >> 4;    // 0..3
  const int lan7 = lane & 7;     // == frag-row & 7 (bases are multiples of 16)

  f32x4  acc[8][4] = {};
  bf16x8 bf[4][2];               // B frags [n][kk], loaded each P0, live all tile

#define PHASE(qq, bb, DO_B, W12, STAGES, ENDW)                                   \
  {                                                                              \
    bf16x8 af[2][2];                                                             \
    _Pragma("unroll")                                                            \
    for (int mi = 0; mi < 2; ++mi)                                               \
      _Pragma("unroll")                                                          \
      for (int kk = 0; kk < 2; ++kk)                                             \
        af[mi][kk] = *(const bf16x8*)&As[bb][(wm*128 + (2*(qq)+mi)*16 + rsel)*BK \
                                             + ((((kk<<2)+ksl) ^ lan7) << 3)];   \
    if (DO_B) {                                                                  \
      _Pragma("unroll")                                                          \
      for (int n = 0; n < 4; ++n)                                                \
        _Pragma("unroll")                                                        \
        for (int kk = 0; kk < 2; ++kk)                                           \
          bf[n][kk] = *(const bf16x8*)&Bs[bb][(wn*64 + n*16 + rsel)*BK           \
                                              + ((((kk<<2)+ksl) ^ lan7) << 3)];  \
    }                                                                            \
    STAGES;                                                                      \
    if (W12) lgkm8();                                                            \
    __builtin_amdgcn_s_barrier();                                                \
    lgkm0();                                                                     \
    __builtin_amdgcn_s_setprio(1);                                               \
    _Pragma("unroll")                                                            \
    for (int kk = 0; kk < 2; ++kk)                                               \
      _Pragma("unroll")                                                          \
      for (int mi = 0; mi < 2; ++mi)                                             \
        _Pragma("unroll")                                                        \
        for (int n = 0; n < 4; ++n)                                              \
          acc[2*(qq)+mi][n] = __builtin_amdgcn_mfma_f32_16x16x32_bf16(           \
              af[mi][kk], bf[n][kk], acc[2*(qq)+mi][n], 0, 0, 0);                \
    __builtin_amdgcn_s_setprio(0);                                               \
    ENDW;                                                                        \
    __builtin_amdgcn_s_barrier();                                                \
  }

  const int NT = K / BK;   // even, >= 6 required (guarded by launcher)

  // Prologue: tile0 full (8 chunks) + tile1 partial (B0-3, A0, A2).
  STAGE_B(0,0,0); STAGE_B(0,1,0); STAGE_B(0,2,0); STAGE_B(0,3,0);
  STAGE_A(0,0,0); STAGE_A(0,2,0); STAGE_A(0,1,0); STAGE_A(0,3,0);
  STAGE_B(1,0,BK); STAGE_B(1,1,BK); STAGE_B(1,2,BK); STAGE_B(1,3,BK);
  STAGE_A(1,0,BK); STAGE_A(1,2,BK);
  vmwait<6>();                         // tile0's 8 retired; tile1's 6 in flight
  __builtin_amdgcn_s_barrier();

  // Steady loop: 2 K-tiles per iteration, literal buffer indices, branch-free.
  // t = 0, 2, ..., NT-4.  (iter stages tile t+2 fully and tile t+3's first 6)
  for (int t = 0; t < NT - 3; t += 2) {
    const long kt1 = (long)(t + 1) * BK;
    const long kt2 = (long)(t + 2) * BK;
    const long kt3 = (long)(t + 3) * BK;
    // tile t  (buf 0)
    PHASE(0, 0, 1, 1, { STAGE_A(1, 1, kt1); STAGE_A(1, 3, kt1); }, (void)0)
    PHASE(1, 0, 0, 0, { STAGE_B(0, 0, kt2); STAGE_B(0, 1, kt2); }, (void)0)
    PHASE(2, 0, 0, 0, { STAGE_B(0, 2, kt2); STAGE_B(0, 3, kt2); }, (void)0)
    PHASE(3, 0, 0, 0, { STAGE_A(0, 0, kt2); STAGE_A(0, 2, kt2); }, vmwait<6>())
    // tile t+1 (buf 1)
    PHASE(0, 1, 1, 1, { STAGE_A(0, 1, kt2); STAGE_A(0, 3, kt2); }, (void)0)
    PHASE(1, 1, 0, 0, { STAGE_B(1, 0, kt3); STAGE_B(1, 1, kt3); }, (void)0)
    PHASE(2, 1, 0, 0, { STAGE_B(1, 2, kt3); STAGE_B(1, 3, kt3); }, (void)0)
    PHASE(3, 1, 0, 0, { STAGE_A(1, 0, kt3); STAGE_A(1, 2, kt3); }, vmwait<6>())
  }
  {  // Tail pair: tiles NT-2 (buf 0), NT-1 (buf 1).
    const long kt1 = (long)(NT - 1) * BK;
    PHASE(0, 0, 1, 1, { STAGE_A(1, 1, kt1); STAGE_A(1, 3, kt1); }, (void)0)
    PHASE(1, 0, 0, 0, (void)0, (void)0)
    PHASE(2, 0, 0, 0, (void)0, (void)0)
    PHASE(3, 0, 0, 0, (void)0, vmwait<0>())   // drain tile NT-1's 8
    PHASE(0, 1, 1, 0, (void)0, (void)0)
    PHASE(1, 1, 0, 0, (void)0, (void)0)
    PHASE(2, 1, 0, 0, (void)0, (void)0)
    PHASE(3, 1, 0, 0, (void)0, (void)0)
  }
#undef PHASE
#undef STAGE_A
#undef STAGE_B

  // Epilogue. C/D: col = lane&15, row = (lane>>4)*4 + j
  float sc[4], bv[4];
  #pragma unroll
  for (int n = 0; n < 4; ++n) {
    const long gcol = col0 + wn * 64 + n * 16 + rsel;
    sc[n] = scale[gcol];
    bv[n] = bias[gcol];
  }
  #pragma unroll
  for (int m = 0; m < 8; ++m) {
    const long grow = row0 + wm * 128 + m * 16 + ksl * 4;
    #pragma unroll
    for (int n = 0; n < 4; ++n) {
      const long gcol = col0 + wn * 64 + n * 16 + rsel;
      float* o = C + grow * (long)N + gcol;
      #pragma unroll
      for (int j = 0; j < 4; ++j)
        o[(long)j * N] = acc[m][n][j] * sc[n] + bv[n];
    }
  }
}

// ---- fallback (ws too small / odd shape): reg-staged 128x128, inline dequant ----
__global__ __launch_bounds__(256)
void qlin_gemm_small(const float* __restrict__ Af, const int* __restrict__ Bi,
                     const int* __restrict__ zp,
                     const float* __restrict__ scale, const float* __restrict__ bias,
                     float* __restrict__ C, int M, int N, int K) {
  __shared__ alignas(16) __bf16 As[128 * 64];
  __shared__ alignas(16) __bf16 Bs[128 * 64];
  const int tid = threadIdx.x, wave = tid >> 6, lane = tid & 63;
  int bid = blockIdx.x, nwg = gridDim.x, swz = bid;
  if ((nwg & 7) == 0) swz = (bid & 7) * (nwg >> 3) + (bid >> 3);
  const int ntn = N / 128;
  const long row0 = (long)(swz / ntn) * 128, col0 = (long)(swz % ntn) * 128;
  const int wr = wave >> 1, wc = wave & 1;
  f32x4 acc[4][4] = {};
  for (int kt = 0; kt < K; kt += 64) {
    #pragma unroll
    for (int i = 0; i < 4; ++i) {
      const int flat = i * 2048 + tid * 8;
      const int r = flat >> 6, cc = flat & 63;
      const int wcc = ((cc >> 3) ^ (r & 7)) << 3;
      const float* g = Af + (row0 + r) * (long)K + kt + cc;
      float4 f0 = *(const float4*)g; float4 f1 = *(const float4*)(g + 4);
      bf16x8 v;
      v[0]=(__bf16)f0.x; v[1]=(__bf16)f0.y; v[2]=(__bf16)f0.z; v[3]=(__bf16)f0.w;
      v[4]=(__bf16)f1.x; v[5]=(__bf16)f1.y; v[6]=(__bf16)f1.z; v[7]=(__bf16)f1.w;
      *(bf16x8*)(As + r * 64 + wcc) = v;
    }
    #pragma unroll
    for (int i = 0; i < 4; ++i) {
      const int flat = i * 2048 + tid * 8;
      const int r = flat >> 6, cc = flat & 63;
      const int wcc = ((cc >> 3) ^ (r & 7)) << 3;
      const long grow = col0 + r;
      const int z = zp[grow];
      const int* g = Bi + grow * (long)K + kt + cc;
      int4 a = *(const int4*)g; int4 b = *(const int4*)(g + 4);
      bf16x8 v;
      v[0]=(__bf16)(float)(a.x-z); v[1]=(__bf16)(float)(a.y-z);
      v[2]=(__bf16)(float)(a.z-z); v[3]=(__bf16)(float)(a.w-z);
      v[4]=(__bf16)(float)(b.x-z); v[5]=(__bf16)(float)(b.y-z);
      v[6]=(__bf16)(float)(b.z-z); v[7]=(__bf16)(float)(b.w-z);
      *(bf16x8*)(Bs + r * 64 + wcc) = v;
    }
    __syncthreads();
    #pragma unroll
    for (int kk = 0; kk < 2; ++kk) {
      bf16x8 af[4], bfr[4];
      const int rs = lane & 15, ks = kk * 4 + (lane >> 4);
      const int rd = (ks ^ (lane & 7)) << 3;
      #pragma unroll
      for (int m = 0; m < 4; ++m) af[m] = *(const bf16x8*)(As + (wr*64 + m*16 + rs)*64 + rd);
      #pragma unroll
      for (int n = 0; n < 4; ++n) bfr[n] = *(const bf16x8*)(Bs + (wc*64 + n*16 + rs)*64 + rd);
      #pragma unroll
      for (int m = 0; m < 4; ++m)
        #pragma unroll
        for (int n = 0; n < 4; ++n)
          acc[m][n] = __builtin_amdgcn_mfma_f32_16x16x32_bf16(af[m], bfr[n], acc[m][n], 0, 0, 0);
    }
    __syncthreads();
  }
  #pragma unroll
  for (int m = 0; m < 4; ++m) {
    const long grow = row0 + wr * 64 + m * 16 + ((lane >> 4) << 2);
    #pragma unroll
    for (int n = 0; n < 4; ++n) {
      const long gcol = col0 + wc * 64 + n * 16 + (lane & 15);
      const float s = scale[gcol], bb2 = bias[gcol];
      float* o = C + grow * (long)N + gcol;
      #pragma unroll
      for (int j = 0; j < 4; ++j) o[(long)j * N] = acc[m][n][j] * s + bb2;
    }
  }
}

extern "C" void kernel_launch(void* const* d_in, const int* in_sizes, int n_in,
                              void* d_out, int out_size, void* d_ws, size_t ws_size,
                              hipStream_t stream) {
  const float* x    = (const float*)d_in[0];
  const int*   wint = (const int*)d_in[1];
  const float* wsc  = (const float*)d_in[2];
  const int*   wzp  = (const int*)d_in[3];
  const float* bias = (const float*)d_in[4];
  float* out = (float*)d_out;

  const int N = in_sizes[4];            // 16384 (OUT)
  const int K = in_sizes[1] / N;        // 4096  (IN)
  const int M = in_sizes[0] / K;        // 8192  (B*S)

  const size_t xbytes = (size_t)M * K * sizeof(__bf16);
  const size_t wbytes = (size_t)N * K * sizeof(__bf16);
  const int NT = K / BK;

  if (ws_size >= xbytes + wbytes && (M % BM) == 0 && (N % BN) == 0 &&
      (K % BK) == 0 && NT >= 6 && (NT % 2) == 0) {
    __bf16* xb = (__bf16*)d_ws;
    __bf16* wb = (__bf16*)((char*)d_ws + xbytes);
    cvt_x_kernel<<<2048, 256, 0, stream>>>(x, xb, (long)M * K);
    cvt_w_kernel<<<2048, 256, 0, stream>>>(wint, wzp, wb, K, (long)N * K);
    const int grid = (M / BM) * (N / BN); // 32 * 64 = 2048
    qlin_gemm<<<grid, THREADS, 0, stream>>>(xb, wb, wsc, bias, out, M, N, K);
  } else {
    const int grid = (M / 128) * (N / 128);
    qlin_gemm_small<<<grid, 256, 0, stream>>>(x, wint, wzp, wsc, bias, out, M, N, K);
  }
}

// Round 9
// 1217.692 us; speedup vs baseline: 3.5386x; 1.1134x over previous
//
#include <hip/hip_runtime.h>
#include <hip/hip_bf16.h>

typedef __bf16 bf16x8 __attribute__((ext_vector_type(8)));
typedef float  f32x4  __attribute__((ext_vector_type(4)));

#define BM 256
#define BN 256
#define BK 64
#define THREADS 512

__device__ __forceinline__ void gload_lds16(const void* g, void* l) {
  __builtin_amdgcn_global_load_lds(
      (const __attribute__((address_space(1))) void*)g,
      (__attribute__((address_space(3))) void*)l, 16, 0, 0);
}

// Bare counted waits (round-6 lesson: a ":::memory" clobber forces a
// conservative vmcnt(0) drain). Ordering vs C++ LDS reads is pinned with
// __builtin_amdgcn_sched_barrier(0) at the call sites.
template<int N> __device__ __forceinline__ void vmwait() {
  if constexpr (N == 0)      asm volatile("s_waitcnt vmcnt(0)");
  else if constexpr (N == 8) asm volatile("s_waitcnt vmcnt(8)");
}

// ---- fp32 -> bf16 (RNE) ----
__global__ void cvt_x_kernel(const float* __restrict__ in, __bf16* __restrict__ out, long n) {
  long i0 = ((long)blockIdx.x * blockDim.x + threadIdx.x) * 8;
  long stride = (long)gridDim.x * blockDim.x * 8;
  for (long i = i0; i < n; i += stride) {
    float4 f0 = *(const float4*)(in + i);
    float4 f1 = *(const float4*)(in + i + 4);
    bf16x8 v;
    v[0] = (__bf16)f0.x; v[1] = (__bf16)f0.y; v[2] = (__bf16)f0.z; v[3] = (__bf16)f0.w;
    v[4] = (__bf16)f1.x; v[5] = (__bf16)f1.y; v[6] = (__bf16)f1.z; v[7] = (__bf16)f1.w;
    *(bf16x8*)(out + i) = v;
  }
}

// ---- (int32 weight - zp) -> bf16, EXACT for |v|<=255 ----
__global__ void cvt_w_kernel(const int* __restrict__ w, const int* __restrict__ zp,
                             __bf16* __restrict__ out, int K, long n) {
  long i0 = ((long)blockIdx.x * blockDim.x + threadIdx.x) * 8;
  long stride = (long)gridDim.x * blockDim.x * 8;
  for (long i = i0; i < n; i += stride) {
    int4 a = *(const int4*)(w + i);
    int4 b = *(const int4*)(w + i + 4);
    int z = zp[i / K];
    bf16x8 v;
    v[0] = (__bf16)(float)(a.x - z); v[1] = (__bf16)(float)(a.y - z);
    v[2] = (__bf16)(float)(a.z - z); v[3] = (__bf16)(float)(a.w - z);
    v[4] = (__bf16)(float)(b.x - z); v[5] = (__bf16)(float)(b.y - z);
    v[6] = (__bf16)(float)(b.z - z); v[7] = (__bf16)(float)(b.w - z);
    *(bf16x8*)(out + i) = v;
  }
}

// ====== 256x256 GEMM: ONE scheduling region per K-tile, 2 barriers/tile ======
// Round-8 audit: the per-phase skeleton (8 barriers/K-tile) forces LDS-read
// bursts and MFMA bursts to run strictly serially -> 6372 cy/K-tile vs a
// 2480-cy MFMA floor (MfmaUtil capped ~38%, measured 37.7%). Fix: all 24
// ds_reads + 64 MFMAs of a tile in one fence-free region -> compiler emits
// fine-grained counted lgkmcnt (m97-verified), reads of quadrant q+1 stream
// while quadrant q's MFMAs run. Per tile:
//   setprio(1) [bf x8; {af_q x4; MFMA_q x16} x4] setprio(0)
//   s_barrier              (i)  all waves' reads of buf b complete (each read
//                               fed an MFMA -> compiler lgkmcnt before it)
//   sched_barrier(0)            stages must not hoist above (i): raw s_barrier
//                               is NOT an LLVM memory fence
//   8x global_load_lds t+2 -> buf b   (WAR-safe after (i))
//   vmcnt(8)                    per-wave: retires tile t+1's 8-load batch
//   s_barrier              (ii) buf b^1 fully landed for ALL waves
//   sched_barrier(0)            next tile's reads must not hoist above vmcnt
// RAW: batches are exactly 8 loads/tile/wave, issued in tile order; at the
// vmcnt(8), outstanding = t+1's 8 + t+2's 8 -> retires t+1 exactly.
// Tails (NT-2: no stage, vmcnt(0); NT-1: no stage) peeled branch-free
// (round-5 lesson: in-loop drain branch spilled acc -> 3x slowdown).
__global__ __launch_bounds__(THREADS, 2)
void qlin_gemm(const __bf16* __restrict__ A, const __bf16* __restrict__ B,
               const float* __restrict__ scale, const float* __restrict__ bias,
               float* __restrict__ C, int M, int N, int K) {
  __shared__ alignas(16) __bf16 As[2][BM * BK];
  __shared__ alignas(16) __bf16 Bs[2][BN * BK];

  const int tid  = threadIdx.x;
  const int wave = tid >> 6;
  const int lane = tid & 63;
  const int wm = wave >> 2, wn = wave & 3;       // 2x4 waves; per-wave 128x64

  int bid = blockIdx.x, nwg = gridDim.x, swz = bid;
  if ((nwg & 7) == 0) swz = (bid & 7) * (nwg >> 3) + (bid >> 3);
  const int ntn = N / BN;
  const long row0 = (long)(swz / ntn) * BM;
  const long col0 = (long)(swz % ntn) * BN;

  const __bf16* Ag = A + row0 * (long)K;
  const __bf16* Bg = B + col0 * (long)K;

  // staging: chunk c = rows [c*64, c*64+64); wave-uniform LDS base; HW adds lane*16B
  const int srow = wave * 8 + (lane >> 3);            // row within chunk
  const int kswz = ((lane & 7) ^ (lane >> 3)) * 8;    // pre-swizzled k elems (T2)

#define STAGE_A(b, c, kt) gload_lds16(Ag + (long)((c)*64 + srow) * K + (kt) + kswz, \
                                      &As[b][(c)*4096 + wave*512])
#define STAGE_B(b, c, kt) gload_lds16(Bg + (long)((c)*64 + srow) * K + (kt) + kswz, \
                                      &Bs[b][(c)*4096 + wave*512])
#define STAGE8(b, kt) { STAGE_B(b,0,kt); STAGE_B(b,1,kt); STAGE_B(b,2,kt); STAGE_B(b,3,kt); \
                        STAGE_A(b,0,kt); STAGE_A(b,1,kt); STAGE_A(b,2,kt); STAGE_A(b,3,kt); }

  const int rsel = lane & 15;
  const int ksl  = lane >> 4;    // 0..3
  const int lan7 = lane & 7;     // == frag-row & 7 (bases are multiples of 16)

  f32x4  acc[8][4] = {};
  bf16x8 bf[4][2];               // B frags [n][kk], live across one tile

#define TILE(bb, STAGES, ENDW)                                                   \
  {                                                                              \
    __builtin_amdgcn_s_setprio(1);                                               \
    _Pragma("unroll")                                                            \
    for (int n = 0; n < 4; ++n)                                                  \
      _Pragma("unroll")                                                          \
      for (int kk = 0; kk < 2; ++kk)                                             \
        bf[n][kk] = *(const bf16x8*)&Bs[bb][(wn*64 + n*16 + rsel)*BK             \
                                            + ((((kk<<2)+ksl) ^ lan7) << 3)];    \
    _Pragma("unroll")                                                            \
    for (int q = 0; q < 4; ++q) {                                                \
      bf16x8 af[2][2];                                                           \
      _Pragma("unroll")                                                          \
      for (int mi = 0; mi < 2; ++mi)                                             \
        _Pragma("unroll")                                                        \
        for (int kk = 0; kk < 2; ++kk)                                           \
          af[mi][kk] = *(const bf16x8*)&As[bb][(wm*128 + (2*q+mi)*16 + rsel)*BK  \
                                               + ((((kk<<2)+ksl) ^ lan7) << 3)]; \
      _Pragma("unroll")                                                          \
      for (int kk = 0; kk < 2; ++kk)                                             \
        _Pragma("unroll")                                                        \
        for (int mi = 0; mi < 2; ++mi)                                           \
          _Pragma("unroll")                                                      \
          for (int n = 0; n < 4; ++n)                                            \
            acc[2*q+mi][n] = __builtin_amdgcn_mfma_f32_16x16x32_bf16(            \
                af[mi][kk], bf[n][kk], acc[2*q+mi][n], 0, 0, 0);                 \
    }                                                                            \
    __builtin_amdgcn_s_setprio(0);                                               \
    __builtin_amdgcn_s_barrier();                                                \
    __builtin_amdgcn_sched_barrier(0);                                           \
    STAGES;                                                                      \
    ENDW;                                                                        \
    __builtin_amdgcn_s_barrier();                                                \
    __builtin_amdgcn_sched_barrier(0);                                           \
  }

  const int NT = K / BK;   // even, >= 6 (guarded by launcher)

  // Prologue: stage tile0 -> buf0, tile1 -> buf1; land tile0 before entering.
  STAGE8(0, 0)
  STAGE8(1, BK)
  vmwait<8>();                       // tile0's 8 retired; tile1's 8 in flight
  __builtin_amdgcn_s_barrier();
  __builtin_amdgcn_sched_barrier(0);

  // Steady: pairs (t, t+1), literal bufs (0,1); tile t stages t+2.
  // t = 0, 2, ..., NT-4  -> covers tiles 0..NT-3, stage targets 2..NT-1.
  for (int t = 0; t < NT - 3; t += 2) {
    const long kt2 = (long)(t + 2) * BK;
    const long kt3 = (long)(t + 3) * BK;
    TILE(0, STAGE8(0, kt2), vmwait<8>())
    TILE(1, STAGE8(1, kt3), vmwait<8>())
  }
  TILE(0, (void)0, vmwait<0>())      // tile NT-2: drain tile NT-1's batch
  TILE(1, (void)0, (void)0)          // tile NT-1: pure compute
#undef TILE
#undef STAGE8
#undef STAGE_A
#undef STAGE_B

  // Epilogue. C/D: col = lane&15, row = (lane>>4)*4 + j
  float sc[4], bv[4];
  #pragma unroll
  for (int n = 0; n < 4; ++n) {
    const long gcol = col0 + wn * 64 + n * 16 + rsel;
    sc[n] = scale[gcol];
    bv[n] = bias[gcol];
  }
  #pragma unroll
  for (int m = 0; m < 8; ++m) {
    const long grow = row0 + wm * 128 + m * 16 + ksl * 4;
    #pragma unroll
    for (int n = 0; n < 4; ++n) {
      const long gcol = col0 + wn * 64 + n * 16 + rsel;
      float* o = C + grow * (long)N + gcol;
      #pragma unroll
      for (int j = 0; j < 4; ++j)
        o[(long)j * N] = acc[m][n][j] * sc[n] + bv[n];
    }
  }
}

// ---- fallback (ws too small / odd shape): reg-staged 128x128, inline dequant ----
__global__ __launch_bounds__(256)
void qlin_gemm_small(const float* __restrict__ Af, const int* __restrict__ Bi,
                     const int* __restrict__ zp,
                     const float* __restrict__ scale, const float* __restrict__ bias,
                     float* __restrict__ C, int M, int N, int K) {
  __shared__ alignas(16) __bf16 As[128 * 64];
  __shared__ alignas(16) __bf16 Bs[128 * 64];
  const int tid = threadIdx.x, wave = tid >> 6, lane = tid & 63;
  int bid = blockIdx.x, nwg = gridDim.x, swz = bid;
  if ((nwg & 7) == 0) swz = (bid & 7) * (nwg >> 3) + (bid >> 3);
  const int ntn = N / 128;
  const long row0 = (long)(swz / ntn) * 128, col0 = (long)(swz % ntn) * 128;
  const int wr = wave >> 1, wc = wave & 1;
  f32x4 acc[4][4] = {};
  for (int kt = 0; kt < K; kt += 64) {
    #pragma unroll
    for (int i = 0; i < 4; ++i) {
      const int flat = i * 2048 + tid * 8;
      const int r = flat >> 6, cc = flat & 63;
      const int wcc = ((cc >> 3) ^ (r & 7)) << 3;
      const float* g = Af + (row0 + r) * (long)K + kt + cc;
      float4 f0 = *(const float4*)g; float4 f1 = *(const float4*)(g + 4);
      bf16x8 v;
      v[0]=(__bf16)f0.x; v[1]=(__bf16)f0.y; v[2]=(__bf16)f0.z; v[3]=(__bf16)f0.w;
      v[4]=(__bf16)f1.x; v[5]=(__bf16)f1.y; v[6]=(__bf16)f1.z; v[7]=(__bf16)f1.w;
      *(bf16x8*)(As + r * 64 + wcc) = v;
    }
    #pragma unroll
    for (int i = 0; i < 4; ++i) {
      const int flat = i * 2048 + tid * 8;
      const int r = flat >> 6, cc = flat & 63;
      const int wcc = ((cc >> 3) ^ (r & 7)) << 3;
      const long grow = col0 + r;
      const int z = zp[grow];
      const int* g = Bi + grow * (long)K + kt + cc;
      int4 a = *(const int4*)g; int4 b = *(const int4*)(g + 4);
      bf16x8 v;
      v[0]=(__bf16)(float)(a.x-z); v[1]=(__bf16)(float)(a.y-z);
      v[2]=(__bf16)(float)(a.z-z); v[3]=(__bf16)(float)(a.w-z);
      v[4]=(__bf16)(float)(b.x-z); v[5]=(__bf16)(float)(b.y-z);
      v[6]=(__bf16)(float)(b.z-z); v[7]=(__bf16)(float)(b.w-z);
      *(bf16x8*)(Bs + r * 64 + wcc) = v;
    }
    __syncthreads();
    #pragma unroll
    for (int kk = 0; kk < 2; ++kk) {
      bf16x8 af[4], bfr[4];
      const int rs = lane & 15, ks = kk * 4 + (lane >> 4);
      const int rd = (ks ^ (lane & 7)) << 3;
      #pragma unroll
      for (int m = 0; m < 4; ++m) af[m] = *(const bf16x8*)(As + (wr*64 + m*16 + rs)*64 + rd);
      #pragma unroll
      for (int n = 0; n < 4; ++n) bfr[n] = *(const bf16x8*)(Bs + (wc*64 + n*16 + rs)*64 + rd);
      #pragma unroll
      for (int m = 0; m < 4; ++m)
        #pragma unroll
        for (int n = 0; n < 4; ++n)
          acc[m][n] = __builtin_amdgcn_mfma_f32_16x16x32_bf16(af[m], bfr[n], acc[m][n], 0, 0, 0);
    }
    __syncthreads();
  }
  #pragma unroll
  for (int m = 0; m < 4; ++m) {
    const long grow = row0 + wr * 64 + m * 16 + ((lane >> 4) << 2);
    #pragma unroll
    for (int n = 0; n < 4; ++n) {
      const long gcol = col0 + wc * 64 + n * 16 + (lane & 15);
      const float s = scale[gcol], bb2 = bias[gcol];
      float* o = C + grow * (long)N + gcol;
      #pragma unroll
      for (int j = 0; j < 4; ++j) o[(long)j * N] = acc[m][n][j] * s + bb2;
    }
  }
}

extern "C" void kernel_launch(void* const* d_in, const int* in_sizes, int n_in,
                              void* d_out, int out_size, void* d_ws, size_t ws_size,
                              hipStream_t stream) {
  const float* x    = (const float*)d_in[0];
  const int*   wint = (const int*)d_in[1];
  const float* wsc  = (const float*)d_in[2];
  const int*   wzp  = (const int*)d_in[3];
  const float* bias = (const float*)d_in[4];
  float* out = (float*)d_out;

  const int N = in_sizes[4];            // 16384 (OUT)
  const int K = in_sizes[1] / N;        // 4096  (IN)
  const int M = in_sizes[0] / K;        // 8192  (B*S)

  const size_t xbytes = (size_t)M * K * sizeof(__bf16);
  const size_t wbytes = (size_t)N * K * sizeof(__bf16);
  const int NT = K / BK;

  if (ws_size >= xbytes + wbytes && (M % BM) == 0 && (N % BN) == 0 &&
      (K % BK) == 0 && NT >= 6 && (NT % 2) == 0) {
    __bf16* xb = (__bf16*)d_ws;
    __bf16* wb = (__bf16*)((char*)d_ws + xbytes);
    cvt_x_kernel<<<2048, 256, 0, stream>>>(x, xb, (long)M * K);
    cvt_w_kernel<<<2048, 256, 0, stream>>>(wint, wzp, wb, K, (long)N * K);
    const int grid = (M / BM) * (N / BN); // 32 * 64 = 2048
    qlin_gemm<<<grid, THREADS, 0, stream>>>(xb, wb, wsc, bias, out, M, N, K);
  } else {
    const int grid = (M / 128) * (N / 128);
    qlin_gemm_small<<<grid, 256, 0, stream>>>(x, wint, wzp, wsc, bias, out, M, N, K);
  }
}

// Round 10
// 1213.438 us; speedup vs baseline: 3.5510x; 1.0035x over previous
//
#include <hip/hip_runtime.h>
#include <hip/hip_bf16.h>

typedef __bf16 bf16x8 __attribute__((ext_vector_type(8)));
typedef float  f32x4  __attribute__((ext_vector_type(4)));

#define BM 256
#define BN 256
#define BK 64
#define THREADS 512

__device__ __forceinline__ void gload_lds16(const void* g, void* l) {
  __builtin_amdgcn_global_load_lds(
      (const __attribute__((address_space(1))) void*)g,
      (__attribute__((address_space(3))) void*)l, 16, 0, 0);
}

// Bare counted waits (round-6 lesson: ":::memory" clobber => conservative
// vmcnt(0) drain). Ordering vs C++ code pinned with sched_barrier(0).
template<int N> __device__ __forceinline__ void vmwait() {
  if constexpr (N == 0)      asm volatile("s_waitcnt vmcnt(0)");
  else if constexpr (N == 8) asm volatile("s_waitcnt vmcnt(8)");
}

// Round-10 lesson under test: __builtin_amdgcn_s_barrier() emits an S_BARRIER
// MI, and SIInsertWaitcnts inserts a FULL s_waitcnt 0 (vmcnt(0)+lgkmcnt(0))
// before every visible S_BARRIER on gfx9-lineage targets -> our counted
// vmcnt(8) was dead code and every tile drained its just-issued stage loads.
// Inline-asm s_barrier is an INLINEASM MI, invisible to the waitcnt pass
// (HipKittens' pattern). sched_barrier(0) on BOTH sides: without the pre-pin,
// register-only MFMAs can sink past an asm barrier (rule #18), breaking the
// reads-complete-before-barrier WAR invariant.
__device__ __forceinline__ void tile_barrier() {
  __builtin_amdgcn_sched_barrier(0);
  asm volatile("s_barrier");
  __builtin_amdgcn_sched_barrier(0);
}

// ---- fp32 -> bf16 (RNE) ----
__global__ void cvt_x_kernel(const float* __restrict__ in, __bf16* __restrict__ out, long n) {
  long i0 = ((long)blockIdx.x * blockDim.x + threadIdx.x) * 8;
  long stride = (long)gridDim.x * blockDim.x * 8;
  for (long i = i0; i < n; i += stride) {
    float4 f0 = *(const float4*)(in + i);
    float4 f1 = *(const float4*)(in + i + 4);
    bf16x8 v;
    v[0] = (__bf16)f0.x; v[1] = (__bf16)f0.y; v[2] = (__bf16)f0.z; v[3] = (__bf16)f0.w;
    v[4] = (__bf16)f1.x; v[5] = (__bf16)f1.y; v[6] = (__bf16)f1.z; v[7] = (__bf16)f1.w;
    *(bf16x8*)(out + i) = v;
  }
}

// ---- (int32 weight - zp) -> bf16, EXACT for |v|<=255 ----
__global__ void cvt_w_kernel(const int* __restrict__ w, const int* __restrict__ zp,
                             __bf16* __restrict__ out, int K, long n) {
  long i0 = ((long)blockIdx.x * blockDim.x + threadIdx.x) * 8;
  long stride = (long)gridDim.x * blockDim.x * 8;
  for (long i = i0; i < n; i += stride) {
    int4 a = *(const int4*)(w + i);
    int4 b = *(const int4*)(w + i + 4);
    int z = zp[i / K];
    bf16x8 v;
    v[0] = (__bf16)(float)(a.x - z); v[1] = (__bf16)(float)(a.y - z);
    v[2] = (__bf16)(float)(a.z - z); v[3] = (__bf16)(float)(a.w - z);
    v[4] = (__bf16)(float)(b.x - z); v[5] = (__bf16)(float)(b.y - z);
    v[6] = (__bf16)(float)(b.z - z); v[7] = (__bf16)(float)(b.w - z);
    *(bf16x8*)(out + i) = v;
  }
}

// ====== 256x256 GEMM: ONE scheduling region per K-tile, 2 barriers/tile ======
// Per tile (buf b):
//   setprio(1) [bf x8; {af_q x4; MFMA_q x16} x4] setprio(0)
//   tile_barrier (i)   all waves' reads of buf b complete (each read fed an
//                      MFMA above the barrier -> data-dep lgkmcnt)
//   8x global_load_lds tile t+2 -> buf b   (WAR-safe after (i))
//   vmcnt(8)           per-wave: retires tile t+1's 8-load batch exactly
//   tile_barrier (ii)  buf b^1 fully landed for ALL waves
// RAW: batches are exactly 8 loads/tile/wave in tile order; at vmcnt(8),
// outstanding = t+1's 8 + t+2's 8.
// Tails (NT-2: no stage, vmcnt(0); NT-1: no stage) peeled branch-free
// (round-5 lesson: in-loop drain branch spilled acc -> 3x slowdown).
__global__ __launch_bounds__(THREADS, 2)
void qlin_gemm(const __bf16* __restrict__ A, const __bf16* __restrict__ B,
               const float* __restrict__ scale, const float* __restrict__ bias,
               float* __restrict__ C, int M, int N, int K) {
  __shared__ alignas(16) __bf16 As[2][BM * BK];
  __shared__ alignas(16) __bf16 Bs[2][BN * BK];

  const int tid  = threadIdx.x;
  const int wave = tid >> 6;
  const int lane = tid & 63;
  const int wm = wave >> 2, wn = wave & 3;       // 2x4 waves; per-wave 128x64

  int bid = blockIdx.x, nwg = gridDim.x, swz = bid;
  if ((nwg & 7) == 0) swz = (bid & 7) * (nwg >> 3) + (bid >> 3);
  const int ntn = N / BN;
  const long row0 = (long)(swz / ntn) * BM;
  const long col0 = (long)(swz % ntn) * BN;

  const __bf16* Ag = A + row0 * (long)K;
  const __bf16* Bg = B + col0 * (long)K;

  // staging: chunk c = rows [c*64, c*64+64); wave-uniform LDS base; HW adds lane*16B
  const int srow = wave * 8 + (lane >> 3);            // row within chunk
  const int kswz = ((lane & 7) ^ (lane >> 3)) * 8;    // pre-swizzled k elems (T2)

#define STAGE_A(b, c, kt) gload_lds16(Ag + (long)((c)*64 + srow) * K + (kt) + kswz, \
                                      &As[b][(c)*4096 + wave*512])
#define STAGE_B(b, c, kt) gload_lds16(Bg + (long)((c)*64 + srow) * K + (kt) + kswz, \
                                      &Bs[b][(c)*4096 + wave*512])
#define STAGE8(b, kt) { STAGE_B(b,0,kt); STAGE_B(b,1,kt); STAGE_B(b,2,kt); STAGE_B(b,3,kt); \
                        STAGE_A(b,0,kt); STAGE_A(b,1,kt); STAGE_A(b,2,kt); STAGE_A(b,3,kt); }

  const int rsel = lane & 15;
  const int ksl  = lane >> 4;    // 0..3
  const int lan7 = lane & 7;     // == frag-row & 7 (bases are multiples of 16)

  f32x4  acc[8][4] = {};
  bf16x8 bf[4][2];               // B frags [n][kk], live across one tile

#define TILE(bb, STAGES, ENDW)                                                   \
  {                                                                              \
    __builtin_amdgcn_s_setprio(1);                                               \
    _Pragma("unroll")                                                            \
    for (int n = 0; n < 4; ++n)                                                  \
      _Pragma("unroll")                                                          \
      for (int kk = 0; kk < 2; ++kk)                                             \
        bf[n][kk] = *(const bf16x8*)&Bs[bb][(wn*64 + n*16 + rsel)*BK             \
                                            + ((((kk<<2)+ksl) ^ lan7) << 3)];    \
    _Pragma("unroll")                                                            \
    for (int q = 0; q < 4; ++q) {                                                \
      bf16x8 af[2][2];                                                           \
      _Pragma("unroll")                                                          \
      for (int mi = 0; mi < 2; ++mi)                                             \
        _Pragma("unroll")                                                        \
        for (int kk = 0; kk < 2; ++kk)                                           \
          af[mi][kk] = *(const bf16x8*)&As[bb][(wm*128 + (2*q+mi)*16 + rsel)*BK  \
                                               + ((((kk<<2)+ksl) ^ lan7) << 3)]; \
      _Pragma("unroll")                                                          \
      for (int kk = 0; kk < 2; ++kk)                                             \
        _Pragma("unroll")                                                        \
        for (int mi = 0; mi < 2; ++mi)                                           \
          _Pragma("unroll")                                                      \
          for (int n = 0; n < 4; ++n)                                            \
            acc[2*q+mi][n] = __builtin_amdgcn_mfma_f32_16x16x32_bf16(            \
                af[mi][kk], bf[n][kk], acc[2*q+mi][n], 0, 0, 0);                 \
    }                                                                            \
    __builtin_amdgcn_s_setprio(0);                                               \
    tile_barrier();  /* (i) */                                                   \
    STAGES;                                                                      \
    ENDW;                                                                        \
    tile_barrier();  /* (ii) */                                                  \
  }

  const int NT = K / BK;   // even, >= 6 (guarded by launcher)

  // Prologue: stage tile0 -> buf0, tile1 -> buf1; land tile0 before entering.
  STAGE8(0, 0)
  STAGE8(1, BK)
  vmwait<8>();                       // tile0's 8 retired; tile1's 8 in flight
  tile_barrier();

  // Steady: pairs (t, t+1), literal bufs (0,1); tile t stages t+2.
  // t = 0, 2, ..., NT-4  -> covers tiles 0..NT-3, stage targets 2..NT-1.
  for (int t = 0; t < NT - 3; t += 2) {
    const long kt2 = (long)(t + 2) * BK;
    const long kt3 = (long)(t + 3) * BK;
    TILE(0, STAGE8(0, kt2), vmwait<8>())
    TILE(1, STAGE8(1, kt3), vmwait<8>())
  }
  TILE(0, (void)0, vmwait<0>())      // tile NT-2: drain tile NT-1's batch
  TILE(1, (void)0, (void)0)          // tile NT-1: pure compute
#undef TILE
#undef STAGE8
#undef STAGE_A
#undef STAGE_B

  // Epilogue. C/D: col = lane&15, row = (lane>>4)*4 + j
  float sc[4], bv[4];
  #pragma unroll
  for (int n = 0; n < 4; ++n) {
    const long gcol = col0 + wn * 64 + n * 16 + rsel;
    sc[n] = scale[gcol];
    bv[n] = bias[gcol];
  }
  #pragma unroll
  for (int m = 0; m < 8; ++m) {
    const long grow = row0 + wm * 128 + m * 16 + ksl * 4;
    #pragma unroll
    for (int n = 0; n < 4; ++n) {
      const long gcol = col0 + wn * 64 + n * 16 + rsel;
      float* o = C + grow * (long)N + gcol;
      #pragma unroll
      for (int j = 0; j < 4; ++j)
        o[(long)j * N] = acc[m][n][j] * sc[n] + bv[n];
    }
  }
}

// ---- fallback (ws too small / odd shape): reg-staged 128x128, inline dequant ----
__global__ __launch_bounds__(256)
void qlin_gemm_small(const float* __restrict__ Af, const int* __restrict__ Bi,
                     const int* __restrict__ zp,
                     const float* __restrict__ scale, const float* __restrict__ bias,
                     float* __restrict__ C, int M, int N, int K) {
  __shared__ alignas(16) __bf16 As[128 * 64];
  __shared__ alignas(16) __bf16 Bs[128 * 64];
  const int tid = threadIdx.x, wave = tid >> 6, lane = tid & 63;
  int bid = blockIdx.x, nwg = gridDim.x, swz = bid;
  if ((nwg & 7) == 0) swz = (bid & 7) * (nwg >> 3) + (bid >> 3);
  const int ntn = N / 128;
  const long row0 = (long)(swz / ntn) * 128, col0 = (long)(swz % ntn) * 128;
  const int wr = wave >> 1, wc = wave & 1;
  f32x4 acc[4][4] = {};
  for (int kt = 0; kt < K; kt += 64) {
    #pragma unroll
    for (int i = 0; i < 4; ++i) {
      const int flat = i * 2048 + tid * 8;
      const int r = flat >> 6, cc = flat & 63;
      const int wcc = ((cc >> 3) ^ (r & 7)) << 3;
      const float* g = Af + (row0 + r) * (long)K + kt + cc;
      float4 f0 = *(const float4*)g; float4 f1 = *(const float4*)(g + 4);
      bf16x8 v;
      v[0]=(__bf16)f0.x; v[1]=(__bf16)f0.y; v[2]=(__bf16)f0.z; v[3]=(__bf16)f0.w;
      v[4]=(__bf16)f1.x; v[5]=(__bf16)f1.y; v[6]=(__bf16)f1.z; v[7]=(__bf16)f1.w;
      *(bf16x8*)(As + r * 64 + wcc) = v;
    }
    #pragma unroll
    for (int i = 0; i < 4; ++i) {
      const int flat = i * 2048 + tid * 8;
      const int r = flat >> 6, cc = flat & 63;
      const int wcc = ((cc >> 3) ^ (r & 7)) << 3;
      const long grow = col0 + r;
      const int z = zp[grow];
      const int* g = Bi + grow * (long)K + kt + cc;
      int4 a = *(const int4*)g; int4 b = *(const int4*)(g + 4);
      bf16x8 v;
      v[0]=(__bf16)(float)(a.x-z); v[1]=(__bf16)(float)(a.y-z);
      v[2]=(__bf16)(float)(a.z-z); v[3]=(__bf16)(float)(a.w-z);
      v[4]=(__bf16)(float)(b.x-z); v[5]=(__bf16)(float)(b.y-z);
      v[6]=(__bf16)(float)(b.z-z); v[7]=(__bf16)(float)(b.w-z);
      *(bf16x8*)(Bs + r * 64 + wcc) = v;
    }
    __syncthreads();
    #pragma unroll
    for (int kk = 0; kk < 2; ++kk) {
      bf16x8 af[4], bfr[4];
      const int rs = lane & 15, ks = kk * 4 + (lane >> 4);
      const int rd = (ks ^ (lane & 7)) << 3;
      #pragma unroll
      for (int m = 0; m < 4; ++m) af[m] = *(const bf16x8*)(As + (wr*64 + m*16 + rs)*64 + rd);
      #pragma unroll
      for (int n = 0; n < 4; ++n) bfr[n] = *(const bf16x8*)(Bs + (wc*64 + n*16 + rs)*64 + rd);
      #pragma unroll
      for (int m = 0; m < 4; ++m)
        #pragma unroll
        for (int n = 0; n < 4; ++n)
          acc[m][n] = __builtin_amdgcn_mfma_f32_16x16x32_bf16(af[m], bfr[n], acc[m][n], 0, 0, 0);
    }
    __syncthreads();
  }
  #pragma unroll
  for (int m = 0; m < 4; ++m) {
    const long grow = row0 + wr * 64 + m * 16 + ((lane >> 4) << 2);
    #pragma unroll
    for (int n = 0; n < 4; ++n) {
      const long gcol = col0 + wc * 64 + n * 16 + (lane & 15);
      const float s = scale[gcol], bb2 = bias[gcol];
      float* o = C + grow * (long)N + gcol;
      #pragma unroll
      for (int j = 0; j < 4; ++j) o[(long)j * N] = acc[m][n][j] * s + bb2;
    }
  }
}

extern "C" void kernel_launch(void* const* d_in, const int* in_sizes, int n_in,
                              void* d_out, int out_size, void* d_ws, size_t ws_size,
                              hipStream_t stream) {
  const float* x    = (const float*)d_in[0];
  const int*   wint = (const int*)d_in[1];
  const float* wsc  = (const float*)d_in[2];
  const int*   wzp  = (const int*)d_in[3];
  const float* bias = (const float*)d_in[4];
  float* out = (float*)d_out;

  const int N = in_sizes[4];            // 16384 (OUT)
  const int K = in_sizes[1] / N;        // 4096  (IN)
  const int M = in_sizes[0] / K;        // 8192  (B*S)

  const size_t xbytes = (size_t)M * K * sizeof(__bf16);
  const size_t wbytes = (size_t)N * K * sizeof(__bf16);
  const int NT = K / BK;

  if (ws_size >= xbytes + wbytes && (M % BM) == 0 && (N % BN) == 0 &&
      (K % BK) == 0 && NT >= 6 && (NT % 2) == 0) {
    __bf16* xb = (__bf16*)d_ws;
    __bf16* wb = (__bf16*)((char*)d_ws + xbytes);
    cvt_x_kernel<<<2048, 256, 0, stream>>>(x, xb, (long)M * K);
    cvt_w_kernel<<<2048, 256, 0, stream>>>(wint, wzp, wb, K, (long)N * K);
    const int grid = (M / BM) * (N / BN); // 32 * 64 = 2048
    qlin_gemm<<<grid, THREADS, 0, stream>>>(xb, wb, wsc, bias, out, M, N, K);
  } else {
    const int grid = (M / 128) * (N / 128);
    qlin_gemm_small<<<grid, 256, 0, stream>>>(x, wint, wzp, wsc, bias, out, M, N, K);
  }
}